// Round 2
// baseline (41984.277 us; speedup 1.0000x reference)
//
#include <hip/hip_runtime.h>

// ---------------------------------------------------------------------------
// Speller (LAS decoder) on MI355X — round 4 (round-3 resubmission + watchdog).
// Round 2 post-mortem: per-step time 128us with only ~4us of real work.
// Cause: agent-scope release/acquire in gbar emit buffer_wbl2 / buffer_inv
// (full-L2 writeback/invalidate) on gfx950 multi-XCD -> every phase restarts
// with a cold L2 (weights refetched each phase; FETCH 41MB/step) and each
// barrier costs ~37us of cache maintenance.
// Round 3 (container died; no compile/test output -> suspected infra flake):
//  * gbar uses RELAXED agent atomics only (no wbl2/inv anywhere).
//  * all cross-block data (h0b,h1b,hidb,embsel,ctxa,ebuf,sbuf) moves through
//    relaxed agent-scope atomic loads/stores (sc0/sc1 point-coherent).
//  * weights & kv stay plain-cached -> L2-resident across phases.
//  * sc1 hot loops get 1-deep software prefetch (atomic loads aren't
//    reordered by the scheduler).
// Round 4: identical design + watchdog'd barrier. Spin loops are capped
// (~8ms, 40x worst legit wait); on expiry a global abort flag makes every
// remaining barrier exit in ~12us, so a hypothetical livelock terminates
// with wrong results (diagnosable) instead of killing the container.
// ---------------------------------------------------------------------------

typedef __attribute__((ext_vector_type(8))) short s8bf;   // 8 bf16 (4 VGPRs)
typedef __attribute__((ext_vector_type(4))) float f32x4;

#define NBLK 256
#define SCALE_E 0.044194173824159216f   // 1/sqrt(512)
#define GBAR_CAP 131072                 // ~8ms of s_sleep(2) iterations

struct Ptrs {
  const float* enc; const int* elen; const int* y;
  const float* emb;
  const float* Wih0; const float* Whh0; const float* bih0; const float* bhh0;
  const float* Wih1; const float* Whh1; const float* bih1; const float* bhh1;
  const float* Wq; const float* Wk; const float* Wv;
  const float* Wout; const float* bout; const float* bchar;
  unsigned short* kv;     // [64000][1024] bf16: [0,512) keys2 (Wq folded), [512,1024) vals
  unsigned short* W0p;    // [2048][1536] bf16, gate-permuted rows (4d+gate)
  unsigned short* W1p;    // [2048][1024] bf16, gate-permuted
  unsigned short* Wob;    // [512][1024] bf16 (W_out as-is)
  unsigned short* WkvT;   // [1024][512] bf16
  unsigned short* embbf;  // [31][512] bf16
  float* b0p; float* b1p; // [2048] permuted summed biases
  unsigned short* h0b;    // [2][64][512] bf16, parity t&1   (sc1 access only)
  unsigned short* h1b;    // [2][64][512] bf16, parity t&1   (sc1 access only)
  unsigned short* hidb;   // [64][512] bf16, hid of step t-1 (sc1 access only)
  unsigned short* embsel; // [64][512] bf16, emb(argmax(logits_298)) (sc1)
  float* c0s; float* c1s; // [64][512] fp32 cell states (block-private, plain)
  float* ctxa;            // [2][64][512] unnormalized ctx accumulator (atomics+sc1)
  float* ebuf;            // [2][64][1024] unnormalized exp(e) (sc1)
  float* sbuf;            // [2][64] softmax denominators (atomics+sc1)
  int* barArr;            // [256] packed arrival epochs
  int* barRel;            // [256*16] replicated release epochs (64B/block)
  int* abortf;            // [1] watchdog abort flag
  float* out;             // d_out: [64][300][31] logits then [64][300][1000] attn
};

__device__ __forceinline__ unsigned short f2bf(float f) {
  unsigned u = __float_as_uint(f);
  u += 0x7fffu + ((u >> 16) & 1u);          // RNE
  return (unsigned short)(u >> 16);
}
__device__ __forceinline__ float bf2f(unsigned short h) {
  return __uint_as_float(((unsigned)h) << 16);
}
__device__ __forceinline__ float sigm(float x) { return 1.f / (1.f + __expf(-x)); }

// ---- relaxed agent-scope (sc0/sc1) access helpers: single instructions, ----
// ---- no cache-maintenance ops. Used for ALL cross-block communication.  ----
__device__ __forceinline__ float ld_f32_sc(const float* p) {
  return __hip_atomic_load((float*)p, __ATOMIC_RELAXED, __HIP_MEMORY_SCOPE_AGENT);
}
__device__ __forceinline__ void st_f32_sc(float* p, float v) {
  __hip_atomic_store(p, v, __ATOMIC_RELAXED, __HIP_MEMORY_SCOPE_AGENT);
}
__device__ __forceinline__ void st_u32_sc(unsigned* p, unsigned v) {
  __hip_atomic_store(p, v, __ATOMIC_RELAXED, __HIP_MEMORY_SCOPE_AGENT);
}
__device__ __forceinline__ void st_u64_sc(unsigned long long* p, unsigned long long v) {
  __hip_atomic_store(p, v, __ATOMIC_RELAXED, __HIP_MEMORY_SCOPE_AGENT);
}
__device__ __forceinline__ void ld_f2_sc(const float* p, float& a, float& b) {
  unsigned long long u = __hip_atomic_load((unsigned long long*)p, __ATOMIC_RELAXED,
                                           __HIP_MEMORY_SCOPE_AGENT);
  a = __uint_as_float((unsigned)u);
  b = __uint_as_float((unsigned)(u >> 32));
}
__device__ __forceinline__ void ld8f_sc(const float* p, float* x) {
  ld_f2_sc(p + 0, x[0], x[1]); ld_f2_sc(p + 2, x[2], x[3]);
  ld_f2_sc(p + 4, x[4], x[5]); ld_f2_sc(p + 6, x[6], x[7]);
}
__device__ __forceinline__ s8bf ld16_sc(const unsigned short* p) {
  union { unsigned long long u[2]; s8bf v; } w;
  w.u[0] = __hip_atomic_load((unsigned long long*)p, __ATOMIC_RELAXED,
                             __HIP_MEMORY_SCOPE_AGENT);
  w.u[1] = __hip_atomic_load((unsigned long long*)(p + 4), __ATOMIC_RELAXED,
                             __HIP_MEMORY_SCOPE_AGENT);
  return w.v;
}
__device__ __forceinline__ void st16_sc(unsigned short* p, s8bf v) {
  union { s8bf s; unsigned long long u[2]; } w; w.s = v;
  st_u64_sc((unsigned long long*)p, w.u[0]);
  st_u64_sc((unsigned long long*)(p + 4), w.u[1]);
}

// ---------------------------------------------------------------------------
// Fence-free grid barrier with watchdog. All flags are RELAXED agent atomics
// (sc1 point accesses). Data ordering: every wave's pre-s_barrier s_waitcnt
// vmcnt(0) drains its sc1 data stores to the coherence point before tid0
// publishes the arrival epoch; consumers read data via sc1 loads after
// observing the release epoch. No buffer_wbl2 / buffer_inv is ever emitted.
// Watchdog: if a spin exceeds GBAR_CAP (~8ms vs <=200us legit), set abortf;
// all barriers then exit quickly -> terminating wrong-result run, not a hang.
// ---------------------------------------------------------------------------
__device__ __forceinline__ void gbar(const Ptrs& P, int epoch) {
  __syncthreads();
  int bid = blockIdx.x, tid = threadIdx.x;
  if (tid == 0) {
    asm volatile("s_waitcnt vmcnt(0)" ::: "memory");
    __hip_atomic_store(P.barArr + bid, epoch, __ATOMIC_RELAXED, __HIP_MEMORY_SCOPE_AGENT);
  }
  if (bid == 0) {
    if (tid < 64) {
      const int* base = P.barArr + tid * 4;
      int g = 0;
      for (;;) {
        int v0 = __hip_atomic_load(base + 0, __ATOMIC_RELAXED, __HIP_MEMORY_SCOPE_AGENT);
        int v1 = __hip_atomic_load(base + 1, __ATOMIC_RELAXED, __HIP_MEMORY_SCOPE_AGENT);
        int v2 = __hip_atomic_load(base + 2, __ATOMIC_RELAXED, __HIP_MEMORY_SCOPE_AGENT);
        int v3 = __hip_atomic_load(base + 3, __ATOMIC_RELAXED, __HIP_MEMORY_SCOPE_AGENT);
        int ok = (v0 >= epoch) && (v1 >= epoch) && (v2 >= epoch) && (v3 >= epoch);
        if (__all(ok)) break;
        ++g;
        if (g > GBAR_CAP) {
          if (tid == 0)
            __hip_atomic_store(P.abortf, 1, __ATOMIC_RELAXED, __HIP_MEMORY_SCOPE_AGENT);
          break;
        }
        if ((g & 255) == 0) {
          int ab = __hip_atomic_load(P.abortf, __ATOMIC_RELAXED, __HIP_MEMORY_SCOPE_AGENT);
          if (__any(ab)) break;
        }
        __builtin_amdgcn_s_sleep(2);
      }
      for (int j = 0; j < 4; ++j)
        __hip_atomic_store(P.barRel + (tid * 4 + j) * 16, epoch,
                           __ATOMIC_RELAXED, __HIP_MEMORY_SCOPE_AGENT);
    }
    __syncthreads();
  } else {
    if (tid == 0) {
      int g = 0;
      while (__hip_atomic_load(P.barRel + bid * 16, __ATOMIC_RELAXED,
                               __HIP_MEMORY_SCOPE_AGENT) < epoch) {
        ++g;
        if (g > GBAR_CAP) {
          __hip_atomic_store(P.abortf, 1, __ATOMIC_RELAXED, __HIP_MEMORY_SCOPE_AGENT);
          break;
        }
        if ((g & 255) == 0 &&
            __hip_atomic_load(P.abortf, __ATOMIC_RELAXED, __HIP_MEMORY_SCOPE_AGENT))
          break;
        __builtin_amdgcn_s_sleep(2);
      }
    }
    __syncthreads();
  }
}

// ---------------------------------------------------------------------------
// k_init: zero barrier slots, cell states, parity-1 h buffers, ctx/exp bufs
// ---------------------------------------------------------------------------
__global__ void k_init(Ptrs P) {
  int g = blockIdx.x * 256 + threadIdx.x;            // 65536 threads
  if (g < 256) P.barArr[g] = 0;
  if (g == 0) P.abortf[0] = 0;
  for (int i = g; i < 4096; i += 65536) P.barRel[i] = 0;
  for (int i = g; i < 32768; i += 65536) { P.c0s[i] = 0.f; P.c1s[i] = 0.f; }
  for (int i = g; i < 65536; i += 65536) {
    P.h0b[i] = 0; P.h1b[i] = 0; P.ctxa[i] = 0.f;
  }
  for (int i = g; i < 131072; i += 65536) P.ebuf[i] = 0.f;
  if (g < 128) P.sbuf[g] = 0.f;
}

// ---------------------------------------------------------------------------
// k_prep: bf16 weight conversion + gate permutation + Wk@Wq^T fold
// ---------------------------------------------------------------------------
__global__ void k_prep(Ptrs P) {
  int bid = blockIdx.x, tid = threadIdx.x;
  for (int ri = 0; ri < 8; ++ri) {
    int gp = bid * 8 + ri;
    int r = (gp & 3) * 512 + (gp >> 2);
    for (int k = tid; k < 1536; k += 256)
      P.W0p[(size_t)gp * 1536 + k] =
          f2bf(k < 1024 ? P.Wih0[(size_t)r * 1024 + k] : P.Whh0[(size_t)r * 512 + (k - 1024)]);
    for (int k = tid; k < 1024; k += 256)
      P.W1p[(size_t)gp * 1024 + k] =
          f2bf(k < 512 ? P.Wih1[(size_t)r * 512 + k] : P.Whh1[(size_t)r * 512 + (k - 512)]);
    if (tid == 0) {
      P.b0p[gp] = P.bih0[r] + P.bhh0[r];
      P.b1p[gp] = P.bih1[r] + P.bhh1[r];
    }
  }
  for (int ri = 0; ri < 2; ++ri) {
    int n = bid * 2 + ri;
    for (int k = tid; k < 1024; k += 256)
      P.Wob[(size_t)n * 1024 + k] = f2bf(P.Wout[(size_t)n * 1024 + k]);
  }
  {
    int g = bid * 256 + tid;
    if (g < 31 * 512) P.embbf[g] = f2bf(P.emb[g]);
  }
  for (int ri = 0; ri < 4; ++ri) {
    int n = bid * 4 + ri;
    if (n < 512) {
      const float* wq = P.Wq + (size_t)n * 512;
      for (int k = tid; k < 512; k += 256) {
        const float* wk = P.Wk + (size_t)k * 512;
        float s0 = 0.f, s1 = 0.f, s2 = 0.f, s3 = 0.f;
        for (int j = 0; j < 512; j += 4) {
          f32x4 a = *(const f32x4*)(wk + j);
          f32x4 b = *(const f32x4*)(wq + j);
          s0 = fmaf(a[0], b[0], s0); s1 = fmaf(a[1], b[1], s1);
          s2 = fmaf(a[2], b[2], s2); s3 = fmaf(a[3], b[3], s3);
        }
        P.WkvT[(size_t)n * 512 + k] = f2bf((s0 + s1) + (s2 + s3));
      }
    } else {
      for (int k = tid; k < 512; k += 256)
        P.WkvT[(size_t)n * 512 + k] = f2bf(P.Wv[(size_t)k * 512 + (n - 512)]);
    }
  }
}

// ---------------------------------------------------------------------------
// k_kv: kv[m][n] = enc[m][:] @ WkvT[n][:]  (M=64000, N=1024, K=512)
// ---------------------------------------------------------------------------
__global__ __launch_bounds__(1024) void k_kv(Ptrs P) {
  int bid = blockIdx.x, tid = threadIdx.x;
  int w = tid >> 6, ln = tid & 63;
  __shared__ unsigned short lds2[16][16][16];
  int mt = bid * 16 + w;
  bool valid = mt < 4000;
  s8bf afr[16];
  if (valid) {
    const float* ar = P.enc + (size_t)(mt * 16 + (ln & 15)) * 512 + ((ln >> 4) * 8);
    for (int ks = 0; ks < 16; ++ks) {
      f32x4 v0 = *(const f32x4*)(ar + ks * 32);
      f32x4 v1 = *(const f32x4*)(ar + ks * 32 + 4);
      s8bf a;
      a[0] = (short)f2bf(v0[0]); a[1] = (short)f2bf(v0[1]);
      a[2] = (short)f2bf(v0[2]); a[3] = (short)f2bf(v0[3]);
      a[4] = (short)f2bf(v1[0]); a[5] = (short)f2bf(v1[1]);
      a[6] = (short)f2bf(v1[2]); a[7] = (short)f2bf(v1[3]);
      afr[ks] = a;
    }
  }
  for (int nt = 0; nt < 64; ++nt) {
    if (valid) {
      f32x4 acc = {0.f, 0.f, 0.f, 0.f};
      const unsigned short* br = P.WkvT + (size_t)(nt * 16 + (ln & 15)) * 512 + ((ln >> 4) * 8);
      for (int ks = 0; ks < 16; ++ks) {
        s8bf b = *(const s8bf*)(br + ks * 32);
        acc = __builtin_amdgcn_mfma_f32_16x16x32_bf16(afr[ks], b, acc, 0, 0, 0);
      }
      for (int r = 0; r < 4; ++r)
        lds2[w][(ln >> 4) * 4 + r][ln & 15] = f2bf(acc[r]);
    }
    __syncthreads();
    if (valid && ln < 32) {
      int row = ln >> 1, half = ln & 1;
      s8bf v = *(const s8bf*)&lds2[w][row][half * 8];
      *(s8bf*)(P.kv + (size_t)(mt * 16 + row) * 1024 + nt * 16 + half * 8) = v;
    }
    __syncthreads();
  }
}

// ---------------------------------------------------------------------------
// Phase helpers for k_main
// ---------------------------------------------------------------------------
// LSTM0: gates = [emb|ctx(t-1)|h0(t-1)] @ W0p^T; blocks 0..31
__device__ __forceinline__ void lstm0_phase(int bid, int tid, int t, const Ptrs& P,
                                            float (*lds_g)[16][16]) {
  int w = tid >> 6, ln = tid & 63;
  int mt = w & 3, nt = bid * 4 + (w >> 2);
  int brow = mt * 16 + (ln & 15), koff = (ln >> 4) * 8;
  int cur = t & 1, prv = cur ^ 1;
  const unsigned short* bp = P.W0p + (size_t)(nt * 16 + (ln & 15)) * 1536 + koff;
  f32x4 acc = {0.f, 0.f, 0.f, 0.f};
  if (t == 299) {
    const unsigned short* embrow = P.embsel + (size_t)brow * 512 + koff;
    for (int ks = 0; ks < 16; ++ks) {
      s8bf af = ld16_sc(embrow + ks * 32);
      s8bf bf8 = *(const s8bf*)(bp + ks * 32);
      acc = __builtin_amdgcn_mfma_f32_16x16x32_bf16(af, bf8, acc, 0, 0, 0);
    }
  } else {
    int sym = (t == 0) ? 0 : P.y[brow * 300 + t];
    const unsigned short* embrow = P.embbf + (size_t)sym * 512 + koff;
    for (int ks = 0; ks < 16; ++ks) {
      s8bf af = *(const s8bf*)(embrow + ks * 32);
      s8bf bf8 = *(const s8bf*)(bp + ks * 32);
      acc = __builtin_amdgcn_mfma_f32_16x16x32_bf16(af, bf8, acc, 0, 0, 0);
    }
  }
  if (t > 0) {
    float inv = 1.f / ld_f32_sc(P.sbuf + prv * 64 + brow);
    const float* cp = P.ctxa + prv * 32768 + (size_t)brow * 512 + koff;
    float x[8], xn[8];
    ld8f_sc(cp, x);
    for (int ks = 0; ks < 16; ++ks) {
      if (ks < 15) ld8f_sc(cp + (ks + 1) * 32, xn);
      s8bf af;
#pragma unroll
      for (int j = 0; j < 8; ++j) af[j] = (short)f2bf(x[j] * inv);
      s8bf bf8 = *(const s8bf*)(bp + 512 + ks * 32);
      acc = __builtin_amdgcn_mfma_f32_16x16x32_bf16(af, bf8, acc, 0, 0, 0);
#pragma unroll
      for (int j = 0; j < 8; ++j) x[j] = xn[j];
    }
  }
  {
    const unsigned short* hp = P.h0b + prv * 32768 + (size_t)brow * 512 + koff;
    s8bf hc = ld16_sc(hp);
    s8bf hn = hc;
    for (int ks = 0; ks < 16; ++ks) {
      if (ks < 15) hn = ld16_sc(hp + (ks + 1) * 32);
      s8bf bf8 = *(const s8bf*)(bp + 1024 + ks * 32);
      acc = __builtin_amdgcn_mfma_f32_16x16x32_bf16(hc, bf8, acc, 0, 0, 0);
      hc = hn;
    }
  }
  float bias = P.b0p[nt * 16 + (ln & 15)];
  for (int r = 0; r < 4; ++r)
    lds_g[w][(ln >> 4) * 4 + r][ln & 15] = acc[r] + bias;
  __syncthreads();
  int rb = ln >> 2, c = ln & 3;
  float gi = lds_g[w][rb][4 * c + 0];
  float gf = lds_g[w][rb][4 * c + 1];
  float gg = lds_g[w][rb][4 * c + 2];
  float go = lds_g[w][rb][4 * c + 3];
  int bb = mt * 16 + rb, d = nt * 4 + c;
  float co = P.c0s[bb * 512 + d];
  float cn = fmaf(sigm(gf), co, sigm(gi) * tanhf(gg));
  float h = sigm(go) * tanhf(cn);
  P.c0s[bb * 512 + d] = cn;                     // block-private, plain
  unsigned short hb = f2bf(h);
  int pr = __shfl_xor((int)(unsigned)hb, 1);
  if ((ln & 1) == 0) {
    unsigned pk = (unsigned)hb | ((unsigned)pr << 16);
    st_u32_sc((unsigned*)(P.h0b + cur * 32768 + bb * 512 + d), pk);
  }
}

// LSTM1: gates = [h0(t)|h1(t-1)] @ W1p^T; blocks 0..31
__device__ __forceinline__ void lstm1_phase(int bid, int tid, int t, const Ptrs& P,
                                            float (*lds_g)[16][16]) {
  int w = tid >> 6, ln = tid & 63;
  int mt = w & 3, nt = bid * 4 + (w >> 2);
  int brow = mt * 16 + (ln & 15), koff = (ln >> 4) * 8;
  int cur = t & 1, prv = cur ^ 1;
  const unsigned short* bp = P.W1p + (size_t)(nt * 16 + (ln & 15)) * 1024 + koff;
  const unsigned short* h0p = P.h0b + cur * 32768 + (size_t)brow * 512 + koff;
  const unsigned short* h1p = P.h1b + prv * 32768 + (size_t)brow * 512 + koff;
  f32x4 acc = {0.f, 0.f, 0.f, 0.f};
  {
    s8bf hc = ld16_sc(h0p);
    s8bf hn = hc;
    for (int ks = 0; ks < 16; ++ks) {
      if (ks < 15) hn = ld16_sc(h0p + (ks + 1) * 32);
      s8bf bf8 = *(const s8bf*)(bp + ks * 32);
      acc = __builtin_amdgcn_mfma_f32_16x16x32_bf16(hc, bf8, acc, 0, 0, 0);
      hc = hn;
    }
  }
  {
    s8bf hc = ld16_sc(h1p);
    s8bf hn = hc;
    for (int ks = 0; ks < 16; ++ks) {
      if (ks < 15) hn = ld16_sc(h1p + (ks + 1) * 32);
      s8bf bf8 = *(const s8bf*)(bp + 512 + ks * 32);
      acc = __builtin_amdgcn_mfma_f32_16x16x32_bf16(hc, bf8, acc, 0, 0, 0);
      hc = hn;
    }
  }
  float bias = P.b1p[nt * 16 + (ln & 15)];
  for (int r = 0; r < 4; ++r)
    lds_g[w][(ln >> 4) * 4 + r][ln & 15] = acc[r] + bias;
  __syncthreads();
  int rb = ln >> 2, c = ln & 3;
  float gi = lds_g[w][rb][4 * c + 0];
  float gf = lds_g[w][rb][4 * c + 1];
  float gg = lds_g[w][rb][4 * c + 2];
  float go = lds_g[w][rb][4 * c + 3];
  int bb = mt * 16 + rb, d = nt * 4 + c;
  float co = P.c1s[bb * 512 + d];
  float cn = fmaf(sigm(gf), co, sigm(gi) * tanhf(gg));
  float h = sigm(go) * tanhf(cn);
  P.c1s[bb * 512 + d] = cn;                     // block-private, plain
  unsigned short hb = f2bf(h);
  int pr = __shfl_xor((int)(unsigned)hb, 1);
  if ((ln & 1) == 0) {
    unsigned pk = (unsigned)hb | ((unsigned)pr << 16);
    st_u32_sc((unsigned*)(P.h1b + cur * 32768 + bb * 512 + d), pk);
  }
}

// hid(s) = relu([h1(s)|ctx(s)] @ Wout^T + bout); blocks 32..47
__device__ __forceinline__ void hid_phase(int bid, int tid, int s, const Ptrs& P,
                                          float (*lds_g)[16][16]) {
  int w = tid >> 6, ln = tid & 63;
  int nl = w >> 3, kq = (w >> 2) & 1, mt = w & 3;
  int nt = (bid - 32) * 2 + nl;
  int brow = mt * 16 + (ln & 15), koff = (ln >> 4) * 8;
  int par = s & 1;
  const unsigned short* bp = P.Wob + (size_t)(nt * 16 + (ln & 15)) * 1024 + kq * 512 + koff;
  f32x4 acc = {0.f, 0.f, 0.f, 0.f};
  if (kq == 0) {
    const unsigned short* ap = P.h1b + par * 32768 + (size_t)brow * 512 + koff;
    s8bf hc = ld16_sc(ap);
    s8bf hn = hc;
    for (int ks = 0; ks < 16; ++ks) {
      if (ks < 15) hn = ld16_sc(ap + (ks + 1) * 32);
      s8bf bf8 = *(const s8bf*)(bp + ks * 32);
      acc = __builtin_amdgcn_mfma_f32_16x16x32_bf16(hc, bf8, acc, 0, 0, 0);
      hc = hn;
    }
  } else {
    float inv = 1.f / ld_f32_sc(P.sbuf + par * 64 + brow);
    const float* ap = P.ctxa + par * 32768 + (size_t)brow * 512 + koff;
    float x[8], xn[8];
    ld8f_sc(ap, x);
    for (int ks = 0; ks < 16; ++ks) {
      if (ks < 15) ld8f_sc(ap + (ks + 1) * 32, xn);
      s8bf af;
#pragma unroll
      for (int j = 0; j < 8; ++j) af[j] = (short)f2bf(x[j] * inv);
      s8bf bf8 = *(const s8bf*)(bp + ks * 32);
      acc = __builtin_amdgcn_mfma_f32_16x16x32_bf16(af, bf8, acc, 0, 0, 0);
#pragma unroll
      for (int j = 0; j < 8; ++j) x[j] = xn[j];
    }
  }
  for (int r = 0; r < 4; ++r)
    lds_g[w][(ln >> 4) * 4 + r][ln & 15] = acc[r];
  __syncthreads();
  for (int r = 0; r < 2; ++r) {
    int idx = r * 1024 + tid;
    int tile = idx >> 8;                 // 0..7: nl2 = tile>>2, mt2 = tile&3
    int nl2 = tile >> 2, mt2 = tile & 3;
    int rb = (idx >> 4) & 15, cc = idx & 15;
    float hsum = lds_g[nl2 * 8 + mt2][rb][cc] + lds_g[nl2 * 8 + 4 + mt2][rb][cc];
    int ntg = (bid - 32) * 2 + nl2;
    hsum += P.bout[ntg * 16 + cc];
    hsum = fmaxf(hsum, 0.f);
    unsigned short hb = f2bf(hsum);
    int pr = __shfl_xor((int)(unsigned)hb, 1);
    if ((tid & 1) == 0) {
      unsigned pk = (unsigned)hb | ((unsigned)pr << 16);
      st_u32_sc((unsigned*)(P.hidb + (size_t)(mt2 * 16 + rb) * 512 + ntg * 16 + cc), pk);
    }
  }
}

// logits(s) from hidb; blocks 32..39, waves 0..7 (one b per wave)
__device__ __forceinline__ void logits_phase(int bid, int tid, int s, const Ptrs& P,
                                             bool do_argmax) {
  int w = tid >> 6, ln = tid & 63;
  if (w >= 8) return;
  int b = (bid - 32) * 8 + w;
  float hv[8];
  s8bf hh = ld16_sc(P.hidb + (size_t)b * 512 + ln * 8);
  for (int j = 0; j < 8; ++j) hv[j] = bf2f((unsigned short)hh[j]);
  float mx = -3.4e38f; int am = 0;
  for (int v = 0; v < 31; ++v) {
    s8bf ee = *(const s8bf*)(P.embbf + (size_t)v * 512 + ln * 8);
    float p = 0.f;
    for (int j = 0; j < 8; ++j) p = fmaf(bf2f((unsigned short)ee[j]), hv[j], p);
    for (int off = 32; off; off >>= 1) p += __shfl_down(p, off);
    if (ln == 0) {
      float lg = p + P.bchar[v];
      P.out[(size_t)b * 9300 + (size_t)s * 31 + v] = lg;
      if (lg > mx) { mx = lg; am = v; }
    }
  }
  if (do_argmax) {
    am = __shfl(am, 0);
    s8bf v = *(const s8bf*)(P.embbf + (size_t)am * 512 + ln * 8);
    st16_sc(P.embsel + (size_t)b * 512 + ln * 8, v);
  }
}

// attention-plot normalize+write for step s; blocks 48..63
__device__ __forceinline__ void attnnorm_phase(int bid, int tid, int s, const Ptrs& P) {
  int idx = (bid - 48) * 1024 + tid;
  if (idx >= 16000) return;
  int b = idx / 250, r = idx - b * 250;
  int par = s & 1;
  float inv = 1.f / ld_f32_sc(P.sbuf + par * 64 + b);
  const float* eb = P.ebuf + par * 65536 + b * 1024 + r * 4;
  float a0, a1, a2, a3;
  ld_f2_sc(eb, a0, a1); ld_f2_sc(eb + 2, a2, a3);
  f32x4 v;
  v[0] = a0 * inv; v[1] = a1 * inv; v[2] = a2 * inv; v[3] = a3 * inv;
  *(f32x4*)(P.out + 595200 + (size_t)b * 300000 + (size_t)s * 1000 + r * 4) = v;
}

// zero ctxa/sbuf parity t for the upcoming sweep; blocks 40..47
__device__ __forceinline__ void zero_phase(int bid, int tid, int t, const Ptrs& P) {
  int idx = (bid - 40) * 1024 + tid;                 // 0..8191
  unsigned long long* p = (unsigned long long*)(P.ctxa + (t & 1) * 32768 + idx * 4);
  st_u64_sc(p + 0, 0ull);
  st_u64_sc(p + 1, 0ull);
  if (bid == 40 && tid < 64) st_f32_sc(P.sbuf + (t & 1) * 64 + tid, 0.f);
}

// fused attention sweep over kv (keys dot + exp + unnormalized ctx); all blocks
__device__ __forceinline__ void sweep(int bid, int tid, int t, const Ptrs& P,
                                      float (*lds_ctx)[512], float* lds_s) {
  int w = tid >> 6, ln = tid & 63;
  int b = bid >> 2, ch = bid & 3;
  int par = t & 1;
  int len = P.elen[b];
  int t0 = ch * 250;
  int lim = t0 + 250; if (len < lim) lim = len;
  float h1r[8];
  {
    s8bf hh = ld16_sc(P.h1b + par * 32768 + (size_t)b * 512 + ln * 8);
    for (int j = 0; j < 8; ++j) h1r[j] = bf2f((unsigned short)hh[j]);
  }
  float acc[8] = {0.f, 0.f, 0.f, 0.f, 0.f, 0.f, 0.f, 0.f};
  float wsum = 0.f;
  float* eb = P.ebuf + par * 65536 + b * 1024;
  const unsigned short* kvb = P.kv + (size_t)b * 1000 * 1024;
  int tt = t0 + w;
  bool have = tt < lim;
  s8bf kk, vv;
  if (have) {
    const unsigned short* row = kvb + (size_t)tt * 1024 + ln * 8;
    kk = *(const s8bf*)(row);
    vv = *(const s8bf*)(row + 512);
  }
  while (have) {
    int ttn = tt + 16;
    bool haven = ttn < lim;
    s8bf kk2, vv2;
    if (haven) {                                  // prefetch next row
      const unsigned short* row = kvb + (size_t)ttn * 1024 + ln * 8;
      kk2 = *(const s8bf*)(row);
      vv2 = *(const s8bf*)(row + 512);
    }
    float p0 = 0.f, p1 = 0.f;
    for (int j = 0; j < 8; j += 2) {
      p0 = fmaf(bf2f((unsigned short)kk[j]), h1r[j], p0);
      p1 = fmaf(bf2f((unsigned short)kk[j + 1]), h1r[j + 1], p1);
    }
    float p = p0 + p1;
    p += __shfl_xor(p, 32); p += __shfl_xor(p, 16); p += __shfl_xor(p, 8);
    p += __shfl_xor(p, 4);  p += __shfl_xor(p, 2);  p += __shfl_xor(p, 1);
    float pe = __expf(p * SCALE_E);               // |e| small: no max-sub needed
    if (ln == 0) { st_f32_sc(eb + tt, pe); wsum += pe; }
    for (int j = 0; j < 8; ++j)
      acc[j] = fmaf(bf2f((unsigned short)vv[j]), pe, acc[j]);
    kk = kk2; vv = vv2; tt = ttn; have = haven;
  }
  if (ln == 0) lds_s[w] = wsum;
  for (int j = 0; j < 8; ++j) lds_ctx[w][ln * 8 + j] = acc[j];
  __syncthreads();
  if (tid < 512) {
    float s = 0.f;
    for (int i = 0; i < 16; ++i) s += lds_ctx[i][tid];
    unsafeAtomicAdd(P.ctxa + par * 32768 + b * 512 + tid, s);   // memory-side atomic
  }
  if (tid == 0) {
    float s = 0.f;
    for (int i = 0; i < 16; ++i) s += lds_s[i];
    unsafeAtomicAdd(P.sbuf + par * 64 + b, s);
  }
}

// ---------------------------------------------------------------------------
// k_main: persistent decode loop, 3 grid barriers / step
// ---------------------------------------------------------------------------
__global__ __launch_bounds__(1024) void k_main(Ptrs P) {
  __shared__ float lds_g[16][16][16];   // 16 KB GEMM tile buffer
  __shared__ float lds_ctx[16][512];    // 32 KB ctx reduction
  __shared__ float lds_s[16];
  int bid = blockIdx.x, tid = threadIdx.x;
  int ep = 0;

  for (int t = 0; t < 300; ++t) {
    // -- Phase A: LSTM0(t) | hid(t-1) | attn-norm(t-1) ----------------------
    if (bid < 32) lstm0_phase(bid, tid, t, P, lds_g);
    else if (bid < 48) { if (t > 0) hid_phase(bid, tid, t - 1, P, lds_g); }
    else if (bid < 64) { if (t > 0) attnnorm_phase(bid, tid, t - 1, P); }
    gbar(P, ++ep);

    // -- Phase B: LSTM1(t) | logits(t-1) | zero ctxa/sbuf parity t ----------
    if (bid < 32) lstm1_phase(bid, tid, t, P, lds_g);
    else if (bid < 40) { if (t > 0) logits_phase(bid, tid, t - 1, P, false); }
    else if (bid < 48) zero_phase(bid, tid, t, P);
    gbar(P, ++ep);

    // -- Phase C: fused attention sweep -------------------------------------
    sweep(bid, tid, t, P, lds_ctx, lds_s);
    gbar(P, ++ep);

    // -- step 298: need argmax(logits_298) as step-299 input -----------------
    if (t == 298) {
      if (bid >= 32 && bid < 48) hid_phase(bid, tid, 298, P, lds_g);
      gbar(P, ++ep);
      if (bid >= 32 && bid < 40) logits_phase(bid, tid, 298, P, true);
      gbar(P, ++ep);
    }
  }
  // tail: hid(299) + attn(299), then logits(299)
  if (bid >= 32 && bid < 48) hid_phase(bid, tid, 299, P, lds_g);
  else if (bid >= 48 && bid < 64) attnnorm_phase(bid, tid, 299, P);
  gbar(P, ++ep);
  if (bid >= 32 && bid < 40) logits_phase(bid, tid, 299, P, false);
}

// ---------------------------------------------------------------------------
extern "C" void kernel_launch(void* const* d_in, const int* in_sizes, int n_in,
                              void* d_out, int out_size, void* d_ws, size_t ws_size,
                              hipStream_t stream) {
  (void)in_sizes; (void)n_in; (void)out_size; (void)ws_size;
  Ptrs P;
  P.enc   = (const float*)d_in[0];
  P.elen  = (const int*)d_in[1];
  P.y     = (const int*)d_in[2];
  P.emb   = (const float*)d_in[3];
  P.Wih0  = (const float*)d_in[4];
  P.Whh0  = (const float*)d_in[5];
  P.bih0  = (const float*)d_in[6];
  P.bhh0  = (const float*)d_in[7];
  P.Wih1  = (const float*)d_in[8];
  P.Whh1  = (const float*)d_in[9];
  P.bih1  = (const float*)d_in[10];
  P.bhh1  = (const float*)d_in[11];
  P.Wq    = (const float*)d_in[12];
  P.Wk    = (const float*)d_in[13];
  P.Wv    = (const float*)d_in[14];
  P.Wout  = (const float*)d_in[15];
  P.bout  = (const float*)d_in[16];
  P.bchar = (const float*)d_in[17];
  P.out   = (float*)d_out;

  char* ws = (char*)d_ws;
  size_t o = 0;
  auto alloc = [&](size_t n) { char* p = ws + o; o = (o + n + 255) & ~(size_t)255; return p; };
  P.kv     = (unsigned short*)alloc(64000ull * 1024 * 2);   // 131 MB
  P.W0p    = (unsigned short*)alloc(2048ull * 1536 * 2);
  P.W1p    = (unsigned short*)alloc(2048ull * 1024 * 2);
  P.Wob    = (unsigned short*)alloc(512ull * 1024 * 2);
  P.WkvT   = (unsigned short*)alloc(1024ull * 512 * 2);
  P.embbf  = (unsigned short*)alloc(31ull * 512 * 2);
  P.b0p    = (float*)alloc(2048 * 4);
  P.b1p    = (float*)alloc(2048 * 4);
  P.h0b    = (unsigned short*)alloc(2ull * 64 * 512 * 2);
  P.h1b    = (unsigned short*)alloc(2ull * 64 * 512 * 2);
  P.hidb   = (unsigned short*)alloc(64ull * 512 * 2);
  P.embsel = (unsigned short*)alloc(64ull * 512 * 2);
  P.c0s    = (float*)alloc(64ull * 512 * 4);
  P.c1s    = (float*)alloc(64ull * 512 * 4);
  P.ctxa   = (float*)alloc(2ull * 64 * 512 * 4);
  P.ebuf   = (float*)alloc(2ull * 64 * 1024 * 4);
  P.sbuf   = (float*)alloc(2ull * 64 * 4);
  P.barArr = (int*)alloc(256 * 4);
  P.barRel = (int*)alloc(256 * 16 * 4);
  P.abortf = (int*)alloc(4);

  k_init<<<dim3(256), dim3(256), 0, stream>>>(P);
  k_prep<<<dim3(256), dim3(256), 0, stream>>>(P);
  k_kv<<<dim3(256), dim3(1024), 0, stream>>>(P);
  k_main<<<dim3(256), dim3(1024), 0, stream>>>(P);
}

// Round 3
// 41545.023 us; speedup vs baseline: 1.0106x; 1.0106x over previous
//
#include <hip/hip_runtime.h>

// ---------------------------------------------------------------------------
// Speller (LAS decoder) on MI355X — round 5.
// Round-4 post-mortem: fence removal changed NOTHING (137us/step, FETCH
// identical). Barrier-overhead theories dead (5->3 barriers also did nothing).
// Real bottleneck: serial unbatched sc1 load chains (~80-100 dependent fabric
// round trips per step at ~1us each).
// Round 5: latency-batching design.
//  * every cross-block 16-iter load loop stages ALL loads into regs first
//    (one latency instead of 16).
//  * ctx pipeline: new 2-block finalize (in phase A, flag-gated) converts
//    f32 ctxa -> normalized bf16 ctxbf once; consumers do staged bf16 loads;
//    finalize also re-zeroes ctxa (zero_phase deleted); sbuf zeroed in B.
//  * sweep prefetch depth 2.
//  * grid barrier: direct poll of packed arrival slots by all blocks
//    (release hop removed), backoff sleep, watchdog kept.
// ---------------------------------------------------------------------------

typedef __attribute__((ext_vector_type(8))) short s8bf;   // 8 bf16 (4 VGPRs)
typedef __attribute__((ext_vector_type(4))) float f32x4;

#define SCALE_E 0.044194173824159216f   // 1/sqrt(512)
#define GBAR_CAP 16384                  // watchdog cap (~8ms)

struct Ptrs {
  const float* enc; const int* elen; const int* y;
  const float* emb;
  const float* Wih0; const float* Whh0; const float* bih0; const float* bhh0;
  const float* Wih1; const float* Whh1; const float* bih1; const float* bhh1;
  const float* Wq; const float* Wk; const float* Wv;
  const float* Wout; const float* bout; const float* bchar;
  unsigned short* kv;     // [64000][1024] bf16: keys2 (Wq folded) | vals
  unsigned short* W0p;    // [2048][1536] bf16, gate-permuted
  unsigned short* W1p;    // [2048][1024] bf16, gate-permuted
  unsigned short* Wob;    // [512][1024] bf16
  unsigned short* WkvT;   // [1024][512] bf16
  unsigned short* embbf;  // [31][512] bf16
  float* b0p; float* b1p; // [2048] permuted summed biases
  unsigned short* h0b;    // [2][64][512] bf16, parity t&1 (sc1)
  unsigned short* h1b;    // [2][64][512] bf16, parity t&1 (sc1)
  unsigned short* hidb;   // [64][512] bf16 (sc1)
  unsigned short* embsel; // [64][512] bf16 (sc1)
  float* c0s; float* c1s; // [64][512] fp32 cell states (block-private)
  float* ctxa;            // [2][64][512] f32 unnormalized ctx accum (atomics)
  unsigned short* ctxbf;  // [2][64][512] bf16 normalized ctx (finalize out)
  float* ebuf;            // [2][64][1024] unnormalized exp(e) (tails stay 0)
  float* sbuf;            // [2][64] softmax denominators
  int* barArr;            // [256] packed arrival epochs
  int* ctxflag;           // [512] two flag slots at 0 / 256
  int* abortf;            // [1] watchdog abort flag
  float* out;             // d_out: [64][300][31] logits then [64][300][1000] attn
};

__device__ __forceinline__ unsigned short f2bf(float f) {
  unsigned u = __float_as_uint(f);
  u += 0x7fffu + ((u >> 16) & 1u);          // RNE
  return (unsigned short)(u >> 16);
}
__device__ __forceinline__ float bf2f(unsigned short h) {
  return __uint_as_float(((unsigned)h) << 16);
}
__device__ __forceinline__ float sigm(float x) { return 1.f / (1.f + __expf(-x)); }

// ---- relaxed agent-scope access helpers (single L2-bypass instructions) ----
__device__ __forceinline__ float ld_f32_sc(const float* p) {
  return __hip_atomic_load((float*)p, __ATOMIC_RELAXED, __HIP_MEMORY_SCOPE_AGENT);
}
__device__ __forceinline__ void st_f32_sc(float* p, float v) {
  __hip_atomic_store(p, v, __ATOMIC_RELAXED, __HIP_MEMORY_SCOPE_AGENT);
}
__device__ __forceinline__ void st_u32_sc(unsigned* p, unsigned v) {
  __hip_atomic_store(p, v, __ATOMIC_RELAXED, __HIP_MEMORY_SCOPE_AGENT);
}
__device__ __forceinline__ void st_u64_sc(unsigned long long* p, unsigned long long v) {
  __hip_atomic_store(p, v, __ATOMIC_RELAXED, __HIP_MEMORY_SCOPE_AGENT);
}
__device__ __forceinline__ void ld_f2_sc(const float* p, float& a, float& b) {
  unsigned long long u = __hip_atomic_load((unsigned long long*)p, __ATOMIC_RELAXED,
                                           __HIP_MEMORY_SCOPE_AGENT);
  a = __uint_as_float((unsigned)u);
  b = __uint_as_float((unsigned)(u >> 32));
}
__device__ __forceinline__ s8bf ld16_sc(const unsigned short* p) {
  union { unsigned long long u[2]; s8bf v; } w;
  w.u[0] = __hip_atomic_load((unsigned long long*)p, __ATOMIC_RELAXED,
                             __HIP_MEMORY_SCOPE_AGENT);
  w.u[1] = __hip_atomic_load((unsigned long long*)(p + 4), __ATOMIC_RELAXED,
                             __HIP_MEMORY_SCOPE_AGENT);
  return w.v;
}
__device__ __forceinline__ void st16_sc(unsigned short* p, s8bf v) {
  union { s8bf s; unsigned long long u[2]; } w; w.s = v;
  st_u64_sc((unsigned long long*)p, w.u[0]);
  st_u64_sc((unsigned long long*)(p + 4), w.u[1]);
}

// ---------------------------------------------------------------------------
// Grid barrier: direct poll of packed arrival epochs by every block's wave 0.
// Relaxed atomics only. Watchdog -> abortf turns livelock into fast exit.
// ---------------------------------------------------------------------------
__device__ __forceinline__ void gbar(const Ptrs& P, int epoch) {
  __syncthreads();
  int bid = blockIdx.x, tid = threadIdx.x;
  if (tid == 0) {
    asm volatile("s_waitcnt vmcnt(0)" ::: "memory");
    __hip_atomic_store(P.barArr + bid, epoch, __ATOMIC_RELAXED, __HIP_MEMORY_SCOPE_AGENT);
  }
  if (tid < 64) {
    const int* base = P.barArr + tid * 4;
    int g = 0;
    for (;;) {
      int v0 = __hip_atomic_load(base + 0, __ATOMIC_RELAXED, __HIP_MEMORY_SCOPE_AGENT);
      int v1 = __hip_atomic_load(base + 1, __ATOMIC_RELAXED, __HIP_MEMORY_SCOPE_AGENT);
      int v2 = __hip_atomic_load(base + 2, __ATOMIC_RELAXED, __HIP_MEMORY_SCOPE_AGENT);
      int v3 = __hip_atomic_load(base + 3, __ATOMIC_RELAXED, __HIP_MEMORY_SCOPE_AGENT);
      int ok = (v0 >= epoch) && (v1 >= epoch) && (v2 >= epoch) && (v3 >= epoch);
      if (__all(ok)) break;
      ++g;
      if (g > GBAR_CAP) {
        if (tid == 0)
          __hip_atomic_store(P.abortf, 1, __ATOMIC_RELAXED, __HIP_MEMORY_SCOPE_AGENT);
        break;
      }
      if ((g & 63) == 0) {
        int ab = __hip_atomic_load(P.abortf, __ATOMIC_RELAXED, __HIP_MEMORY_SCOPE_AGENT);
        if (__any(ab)) break;
      }
      if (g < 8) __builtin_amdgcn_s_sleep(1);
      else       __builtin_amdgcn_s_sleep(16);
    }
  }
  __syncthreads();
}

// poll the ctx-finalize flag (wave-uniform; one coalesced request per poll)
__device__ __forceinline__ void pollflag(const Ptrs& P, int half, int need) {
  int g = 0;
  while (__hip_atomic_load(P.ctxflag + half * 256, __ATOMIC_RELAXED,
                           __HIP_MEMORY_SCOPE_AGENT) < need) {
    if (++g > GBAR_CAP) break;
    if (g < 8) __builtin_amdgcn_s_sleep(1);
    else       __builtin_amdgcn_s_sleep(8);
  }
}

// ---------------------------------------------------------------------------
// k_init
// ---------------------------------------------------------------------------
__global__ void k_init(Ptrs P) {
  int g = blockIdx.x * 256 + threadIdx.x;            // 65536 threads
  if (g < 256) P.barArr[g] = 0;
  if (g < 512) P.ctxflag[g] = 0;
  if (g == 0) P.abortf[0] = 0;
  for (int i = g; i < 32768; i += 65536) { P.c0s[i] = 0.f; P.c1s[i] = 0.f; }
  for (int i = g; i < 65536; i += 65536) {
    P.h0b[i] = 0; P.h1b[i] = 0; P.ctxa[i] = 0.f;
  }
  for (int i = g; i < 131072; i += 65536) P.ebuf[i] = 0.f;
  if (g < 128) P.sbuf[g] = 0.f;
}

// ---------------------------------------------------------------------------
// k_prep: bf16 weight conversion + gate permutation + Wk@Wq^T fold
// ---------------------------------------------------------------------------
__global__ void k_prep(Ptrs P) {
  int bid = blockIdx.x, tid = threadIdx.x;
  for (int ri = 0; ri < 8; ++ri) {
    int gp = bid * 8 + ri;
    int r = (gp & 3) * 512 + (gp >> 2);
    for (int k = tid; k < 1536; k += 256)
      P.W0p[(size_t)gp * 1536 + k] =
          f2bf(k < 1024 ? P.Wih0[(size_t)r * 1024 + k] : P.Whh0[(size_t)r * 512 + (k - 1024)]);
    for (int k = tid; k < 1024; k += 256)
      P.W1p[(size_t)gp * 1024 + k] =
          f2bf(k < 512 ? P.Wih1[(size_t)r * 512 + k] : P.Whh1[(size_t)r * 512 + (k - 512)]);
    if (tid == 0) {
      P.b0p[gp] = P.bih0[r] + P.bhh0[r];
      P.b1p[gp] = P.bih1[r] + P.bhh1[r];
    }
  }
  for (int ri = 0; ri < 2; ++ri) {
    int n = bid * 2 + ri;
    for (int k = tid; k < 1024; k += 256)
      P.Wob[(size_t)n * 1024 + k] = f2bf(P.Wout[(size_t)n * 1024 + k]);
  }
  {
    int g = bid * 256 + tid;
    if (g < 31 * 512) P.embbf[g] = f2bf(P.emb[g]);
  }
  for (int ri = 0; ri < 4; ++ri) {
    int n = bid * 4 + ri;
    if (n < 512) {
      const float* wq = P.Wq + (size_t)n * 512;
      for (int k = tid; k < 512; k += 256) {
        const float* wk = P.Wk + (size_t)k * 512;
        float s0 = 0.f, s1 = 0.f, s2 = 0.f, s3 = 0.f;
        for (int j = 0; j < 512; j += 4) {
          f32x4 a = *(const f32x4*)(wk + j);
          f32x4 b = *(const f32x4*)(wq + j);
          s0 = fmaf(a[0], b[0], s0); s1 = fmaf(a[1], b[1], s1);
          s2 = fmaf(a[2], b[2], s2); s3 = fmaf(a[3], b[3], s3);
        }
        P.WkvT[(size_t)n * 512 + k] = f2bf((s0 + s1) + (s2 + s3));
      }
    } else {
      for (int k = tid; k < 512; k += 256)
        P.WkvT[(size_t)n * 512 + k] = f2bf(P.Wv[(size_t)k * 512 + (n - 512)]);
    }
  }
}

// ---------------------------------------------------------------------------
// k_kv: kv[m][n] = enc[m][:] @ WkvT[n][:]  (M=64000, N=1024, K=512)
// ---------------------------------------------------------------------------
__global__ __launch_bounds__(1024) void k_kv(Ptrs P) {
  int bid = blockIdx.x, tid = threadIdx.x;
  int w = tid >> 6, ln = tid & 63;
  __shared__ unsigned short lds2[16][16][16];
  int mt = bid * 16 + w;
  bool valid = mt < 4000;
  s8bf afr[16];
  if (valid) {
    const float* ar = P.enc + (size_t)(mt * 16 + (ln & 15)) * 512 + ((ln >> 4) * 8);
    for (int ks = 0; ks < 16; ++ks) {
      f32x4 v0 = *(const f32x4*)(ar + ks * 32);
      f32x4 v1 = *(const f32x4*)(ar + ks * 32 + 4);
      s8bf a;
      a[0] = (short)f2bf(v0[0]); a[1] = (short)f2bf(v0[1]);
      a[2] = (short)f2bf(v0[2]); a[3] = (short)f2bf(v0[3]);
      a[4] = (short)f2bf(v1[0]); a[5] = (short)f2bf(v1[1]);
      a[6] = (short)f2bf(v1[2]); a[7] = (short)f2bf(v1[3]);
      afr[ks] = a;
    }
  }
  for (int nt = 0; nt < 64; ++nt) {
    if (valid) {
      f32x4 acc = {0.f, 0.f, 0.f, 0.f};
      const unsigned short* br = P.WkvT + (size_t)(nt * 16 + (ln & 15)) * 512 + ((ln >> 4) * 8);
      for (int ks = 0; ks < 16; ++ks) {
        s8bf b = *(const s8bf*)(br + ks * 32);
        acc = __builtin_amdgcn_mfma_f32_16x16x32_bf16(afr[ks], b, acc, 0, 0, 0);
      }
      for (int r = 0; r < 4; ++r)
        lds2[w][(ln >> 4) * 4 + r][ln & 15] = f2bf(acc[r]);
    }
    __syncthreads();
    if (valid && ln < 32) {
      int row = ln >> 1, half = ln & 1;
      s8bf v = *(const s8bf*)&lds2[w][row][half * 8];
      *(s8bf*)(P.kv + (size_t)(mt * 16 + row) * 1024 + nt * 16 + half * 8) = v;
    }
    __syncthreads();
  }
}

// ---------------------------------------------------------------------------
// Phase helpers for k_main
// ---------------------------------------------------------------------------
// LSTM0: gates = [emb|ctx(t-1)|h0(t-1)] @ W0p^T; blocks 0..31
__device__ __forceinline__ void lstm0_phase(int bid, int tid, int t, const Ptrs& P,
                                            float (*lds_g)[16][16]) {
  int w = tid >> 6, ln = tid & 63;
  int mt = w & 3, nt = bid * 4 + (w >> 2);
  int brow = mt * 16 + (ln & 15), koff = (ln >> 4) * 8;
  int cur = t & 1, prv = cur ^ 1;
  const unsigned short* bp = P.W0p + (size_t)(nt * 16 + (ln & 15)) * 1536 + koff;
  f32x4 acc = {0.f, 0.f, 0.f, 0.f};
  // -- emb segment --
  if (t == 299) {
    const unsigned short* embrow = P.embsel + (size_t)brow * 512 + koff;
    s8bf er[16];
#pragma unroll
    for (int ks = 0; ks < 16; ++ks) er[ks] = ld16_sc(embrow + ks * 32);
#pragma unroll
    for (int ks = 0; ks < 16; ++ks) {
      s8bf bf8 = *(const s8bf*)(bp + ks * 32);
      acc = __builtin_amdgcn_mfma_f32_16x16x32_bf16(er[ks], bf8, acc, 0, 0, 0);
    }
  } else {
    int sym = (t == 0) ? 0 : P.y[brow * 300 + t];
    const unsigned short* embrow = P.embbf + (size_t)sym * 512 + koff;
#pragma unroll
    for (int ks = 0; ks < 16; ++ks) {
      s8bf af = *(const s8bf*)(embrow + ks * 32);
      s8bf bf8 = *(const s8bf*)(bp + ks * 32);
      acc = __builtin_amdgcn_mfma_f32_16x16x32_bf16(af, bf8, acc, 0, 0, 0);
    }
  }
  // -- h0(t-1) segment (staged sc loads: one latency) --
  {
    const unsigned short* hp = P.h0b + prv * 32768 + (size_t)brow * 512 + koff;
    s8bf hr[16];
#pragma unroll
    for (int ks = 0; ks < 16; ++ks) hr[ks] = ld16_sc(hp + ks * 32);
#pragma unroll
    for (int ks = 0; ks < 16; ++ks) {
      s8bf bf8 = *(const s8bf*)(bp + 1024 + ks * 32);
      acc = __builtin_amdgcn_mfma_f32_16x16x32_bf16(hr[ks], bf8, acc, 0, 0, 0);
    }
  }
  // -- ctx(t-1) segment (flag-gated, normalized bf16, staged) --
  if (t > 0) {
    pollflag(P, mt >> 1, t);
    const unsigned short* cp = P.ctxbf + prv * 32768 + (size_t)brow * 512 + koff;
    s8bf cr[16];
#pragma unroll
    for (int ks = 0; ks < 16; ++ks) cr[ks] = ld16_sc(cp + ks * 32);
#pragma unroll
    for (int ks = 0; ks < 16; ++ks) {
      s8bf bf8 = *(const s8bf*)(bp + 512 + ks * 32);
      acc = __builtin_amdgcn_mfma_f32_16x16x32_bf16(cr[ks], bf8, acc, 0, 0, 0);
    }
  }
  float bias = P.b0p[nt * 16 + (ln & 15)];
  for (int r = 0; r < 4; ++r)
    lds_g[w][(ln >> 4) * 4 + r][ln & 15] = acc[r] + bias;
  __syncthreads();
  int rb = ln >> 2, c = ln & 3;
  float gi = lds_g[w][rb][4 * c + 0];
  float gf = lds_g[w][rb][4 * c + 1];
  float gg = lds_g[w][rb][4 * c + 2];
  float go = lds_g[w][rb][4 * c + 3];
  int bb = mt * 16 + rb, d = nt * 4 + c;
  float co = P.c0s[bb * 512 + d];
  float cn = fmaf(sigm(gf), co, sigm(gi) * tanhf(gg));
  float h = sigm(go) * tanhf(cn);
  P.c0s[bb * 512 + d] = cn;                     // block-private, plain
  unsigned short hb = f2bf(h);
  int pr = __shfl_xor((int)(unsigned)hb, 1);
  if ((ln & 1) == 0) {
    unsigned pk = (unsigned)hb | ((unsigned)pr << 16);
    st_u32_sc((unsigned*)(P.h0b + cur * 32768 + bb * 512 + d), pk);
  }
}

// LSTM1: gates = [h0(t)|h1(t-1)] @ W1p^T; blocks 0..31
__device__ __forceinline__ void lstm1_phase(int bid, int tid, int t, const Ptrs& P,
                                            float (*lds_g)[16][16]) {
  int w = tid >> 6, ln = tid & 63;
  int mt = w & 3, nt = bid * 4 + (w >> 2);
  int brow = mt * 16 + (ln & 15), koff = (ln >> 4) * 8;
  int cur = t & 1, prv = cur ^ 1;
  const unsigned short* bp = P.W1p + (size_t)(nt * 16 + (ln & 15)) * 1024 + koff;
  f32x4 acc = {0.f, 0.f, 0.f, 0.f};
  {
    const unsigned short* h0p = P.h0b + cur * 32768 + (size_t)brow * 512 + koff;
    s8bf hr[16];
#pragma unroll
    for (int ks = 0; ks < 16; ++ks) hr[ks] = ld16_sc(h0p + ks * 32);
#pragma unroll
    for (int ks = 0; ks < 16; ++ks) {
      s8bf bf8 = *(const s8bf*)(bp + ks * 32);
      acc = __builtin_amdgcn_mfma_f32_16x16x32_bf16(hr[ks], bf8, acc, 0, 0, 0);
    }
  }
  {
    const unsigned short* h1p = P.h1b + prv * 32768 + (size_t)brow * 512 + koff;
    s8bf hr[16];
#pragma unroll
    for (int ks = 0; ks < 16; ++ks) hr[ks] = ld16_sc(h1p + ks * 32);
#pragma unroll
    for (int ks = 0; ks < 16; ++ks) {
      s8bf bf8 = *(const s8bf*)(bp + 512 + ks * 32);
      acc = __builtin_amdgcn_mfma_f32_16x16x32_bf16(hr[ks], bf8, acc, 0, 0, 0);
    }
  }
  float bias = P.b1p[nt * 16 + (ln & 15)];
  for (int r = 0; r < 4; ++r)
    lds_g[w][(ln >> 4) * 4 + r][ln & 15] = acc[r] + bias;
  __syncthreads();
  int rb = ln >> 2, c = ln & 3;
  float gi = lds_g[w][rb][4 * c + 0];
  float gf = lds_g[w][rb][4 * c + 1];
  float gg = lds_g[w][rb][4 * c + 2];
  float go = lds_g[w][rb][4 * c + 3];
  int bb = mt * 16 + rb, d = nt * 4 + c;
  float co = P.c1s[bb * 512 + d];
  float cn = fmaf(sigm(gf), co, sigm(gi) * tanhf(gg));
  float h = sigm(go) * tanhf(cn);
  P.c1s[bb * 512 + d] = cn;                     // block-private, plain
  unsigned short hb = f2bf(h);
  int pr = __shfl_xor((int)(unsigned)hb, 1);
  if ((ln & 1) == 0) {
    unsigned pk = (unsigned)hb | ((unsigned)pr << 16);
    st_u32_sc((unsigned*)(P.h1b + cur * 32768 + bb * 512 + d), pk);
  }
}

// hid(s) = relu([h1(s)|ctx(s)] @ Wout^T + bout); blocks 32..47
__device__ __forceinline__ void hid_phase(int bid, int tid, int s, const Ptrs& P,
                                          float (*lds_g)[16][16]) {
  int w = tid >> 6, ln = tid & 63;
  int nl = w >> 3, kq = (w >> 2) & 1, mt = w & 3;
  int nt = (bid - 32) * 2 + nl;
  int brow = mt * 16 + (ln & 15), koff = (ln >> 4) * 8;
  int par = s & 1;
  const unsigned short* bp = P.Wob + (size_t)(nt * 16 + (ln & 15)) * 1024 + kq * 512 + koff;
  f32x4 acc = {0.f, 0.f, 0.f, 0.f};
  const unsigned short* ap;
  if (kq == 0) {
    ap = P.h1b + par * 32768 + (size_t)brow * 512 + koff;
  } else {
    pollflag(P, mt >> 1, s + 1);                // ctx(s) finalized?
    ap = P.ctxbf + par * 32768 + (size_t)brow * 512 + koff;
  }
  {
    s8bf hr[16];
#pragma unroll
    for (int ks = 0; ks < 16; ++ks) hr[ks] = ld16_sc(ap + ks * 32);
#pragma unroll
    for (int ks = 0; ks < 16; ++ks) {
      s8bf bf8 = *(const s8bf*)(bp + ks * 32);
      acc = __builtin_amdgcn_mfma_f32_16x16x32_bf16(hr[ks], bf8, acc, 0, 0, 0);
    }
  }
  for (int r = 0; r < 4; ++r)
    lds_g[w][(ln >> 4) * 4 + r][ln & 15] = acc[r];
  __syncthreads();
  for (int r = 0; r < 2; ++r) {
    int idx = r * 1024 + tid;
    int tile = idx >> 8;                 // 0..7: nl2 = tile>>2, mt2 = tile&3
    int nl2 = tile >> 2, mt2 = tile & 3;
    int rb = (idx >> 4) & 15, cc = idx & 15;
    float hsum = lds_g[nl2 * 8 + mt2][rb][cc] + lds_g[nl2 * 8 + 4 + mt2][rb][cc];
    int ntg = (bid - 32) * 2 + nl2;
    hsum += P.bout[ntg * 16 + cc];
    hsum = fmaxf(hsum, 0.f);
    unsigned short hb = f2bf(hsum);
    int pr = __shfl_xor((int)(unsigned)hb, 1);
    if ((tid & 1) == 0) {
      unsigned pk = (unsigned)hb | ((unsigned)pr << 16);
      st_u32_sc((unsigned*)(P.hidb + (size_t)(mt2 * 16 + rb) * 512 + ntg * 16 + cc), pk);
    }
  }
}

// logits(s) from hidb; blocks 32..39, waves 0..7 (one b per wave)
__device__ __forceinline__ void logits_phase(int bid, int tid, int s, const Ptrs& P,
                                             bool do_argmax) {
  int w = tid >> 6, ln = tid & 63;
  if (w >= 8) return;
  int b = (bid - 32) * 8 + w;
  float hv[8];
  s8bf hh = ld16_sc(P.hidb + (size_t)b * 512 + ln * 8);
  for (int j = 0; j < 8; ++j) hv[j] = bf2f((unsigned short)hh[j]);
  float mx = -3.4e38f; int am = 0;
  for (int v = 0; v < 31; ++v) {
    s8bf ee = *(const s8bf*)(P.embbf + (size_t)v * 512 + ln * 8);
    float p = 0.f;
    for (int j = 0; j < 8; ++j) p = fmaf(bf2f((unsigned short)ee[j]), hv[j], p);
    for (int off = 32; off; off >>= 1) p += __shfl_down(p, off);
    if (ln == 0) {
      float lg = p + P.bchar[v];
      P.out[(size_t)b * 9300 + (size_t)s * 31 + v] = lg;
      if (lg > mx) { mx = lg; am = v; }
    }
  }
  if (do_argmax) {
    am = __shfl(am, 0);
    s8bf v = *(const s8bf*)(P.embbf + (size_t)am * 512 + ln * 8);
    st16_sc(P.embsel + (size_t)b * 512 + ln * 8, v);
  }
}

// attention-plot normalize+write for step s; blocks 48..63 (reads sbuf direct)
__device__ __forceinline__ void attnnorm_phase(int bid, int tid, int s, const Ptrs& P) {
  int idx = (bid - 48) * 1024 + tid;
  if (idx >= 16000) return;
  int b = idx / 250, r = idx - b * 250;
  int par = s & 1;
  float inv = 1.f / ld_f32_sc(P.sbuf + par * 64 + b);
  const float* eb = P.ebuf + par * 65536 + b * 1024 + r * 4;
  float a0, a1, a2, a3;
  ld_f2_sc(eb, a0, a1); ld_f2_sc(eb + 2, a2, a3);
  f32x4 v;
  v[0] = a0 * inv; v[1] = a1 * inv; v[2] = a2 * inv; v[3] = a3 * inv;
  *(f32x4*)(P.out + 595200 + (size_t)b * 300000 + (size_t)s * 1000 + r * 4) = v;
}

// ctx finalize: ctxbf[par] = ctxa[par]/sbuf (bf16), re-zero ctxa[par], set flag.
// Two blocks (blkh = 0/1), each handles 32 batches = 16384 floats.
__device__ __forceinline__ void finalize_phase(int blkh, int tid, int s, const Ptrs& P) {
  int par = s & 1;
  int base = blkh * 16384 + tid * 16;              // 16 consecutive floats, one b
  int b = base >> 9;
  float inv = 1.f / ld_f32_sc(P.sbuf + par * 64 + b);
  float* src = P.ctxa + par * 32768 + base;
  unsigned short* dst = P.ctxbf + par * 32768 + base;
  float x[16];
#pragma unroll
  for (int c = 0; c < 8; ++c) ld_f2_sc(src + 2 * c, x[2 * c], x[2 * c + 1]);
#pragma unroll
  for (int c = 0; c < 4; ++c) {
    unsigned long long u =
        (unsigned long long)f2bf(x[4 * c + 0] * inv) |
        ((unsigned long long)f2bf(x[4 * c + 1] * inv) << 16) |
        ((unsigned long long)f2bf(x[4 * c + 2] * inv) << 32) |
        ((unsigned long long)f2bf(x[4 * c + 3] * inv) << 48);
    st_u64_sc((unsigned long long*)(dst + 4 * c), u);
  }
#pragma unroll
  for (int c = 0; c < 8; ++c)
    st_u64_sc((unsigned long long*)src + c, 0ull);  // re-zero for sweep(t+1)
  __syncthreads();                                   // drains all waves' stores
  if (tid == 0)
    __hip_atomic_store(P.ctxflag + blkh * 256, s + 1, __ATOMIC_RELAXED,
                       __HIP_MEMORY_SCOPE_AGENT);
}

// fused attention sweep (keys dot + exp + unnormalized ctx); all 256 blocks
__device__ __forceinline__ void sweep(int bid, int tid, int t, const Ptrs& P,
                                      float (*lds_ctx)[512], float* lds_s) {
  int w = tid >> 6, ln = tid & 63;
  int b = bid >> 2, ch = bid & 3;
  int par = t & 1;
  int len = P.elen[b];
  int t0 = ch * 250;
  int lim = t0 + 250; if (len < lim) lim = len;
  float h1r[8];
  {
    s8bf hh = ld16_sc(P.h1b + par * 32768 + (size_t)b * 512 + ln * 8);
    for (int j = 0; j < 8; ++j) h1r[j] = bf2f((unsigned short)hh[j]);
  }
  float acc[8] = {0.f, 0.f, 0.f, 0.f, 0.f, 0.f, 0.f, 0.f};
  float wsum = 0.f;
  float* eb = P.ebuf + par * 65536 + b * 1024;
  const unsigned short* kvb = P.kv + (size_t)b * 1000 * 1024;
  int tt = t0 + w;
  s8bf k0, v0, k1, v1;
  bool hv0 = tt < lim, hv1 = (tt + 16) < lim;
  if (hv0) {
    const unsigned short* r = kvb + (size_t)tt * 1024 + ln * 8;
    k0 = *(const s8bf*)r; v0 = *(const s8bf*)(r + 512);
  }
  if (hv1) {
    const unsigned short* r = kvb + (size_t)(tt + 16) * 1024 + ln * 8;
    k1 = *(const s8bf*)r; v1 = *(const s8bf*)(r + 512);
  }
  while (hv0) {
    s8bf k2, v2;
    bool hv2 = (tt + 32) < lim;
    if (hv2) {                                   // prefetch depth 2
      const unsigned short* r = kvb + (size_t)(tt + 32) * 1024 + ln * 8;
      k2 = *(const s8bf*)r; v2 = *(const s8bf*)(r + 512);
    }
    float p0 = 0.f, p1 = 0.f;
    for (int j = 0; j < 8; j += 2) {
      p0 = fmaf(bf2f((unsigned short)k0[j]), h1r[j], p0);
      p1 = fmaf(bf2f((unsigned short)k0[j + 1]), h1r[j + 1], p1);
    }
    float p = p0 + p1;
    p += __shfl_xor(p, 32); p += __shfl_xor(p, 16); p += __shfl_xor(p, 8);
    p += __shfl_xor(p, 4);  p += __shfl_xor(p, 2);  p += __shfl_xor(p, 1);
    float pe = __expf(p * SCALE_E);              // |e| small: no max-sub needed
    if (ln == 0) { st_f32_sc(eb + tt, pe); wsum += pe; }
    for (int j = 0; j < 8; ++j)
      acc[j] = fmaf(bf2f((unsigned short)v0[j]), pe, acc[j]);
    k0 = k1; v0 = v1; hv0 = hv1;
    k1 = k2; v1 = v2; hv1 = hv2;
    tt += 16;
  }
  if (ln == 0) lds_s[w] = wsum;
  for (int j = 0; j < 8; ++j) lds_ctx[w][ln * 8 + j] = acc[j];
  __syncthreads();
  if (tid < 512) {
    float s = 0.f;
    for (int i = 0; i < 16; ++i) s += lds_ctx[i][tid];
    unsafeAtomicAdd(P.ctxa + par * 32768 + b * 512 + tid, s);   // memory-side
  }
  if (tid == 0) {
    float s = 0.f;
    for (int i = 0; i < 16; ++i) s += lds_s[i];
    unsafeAtomicAdd(P.sbuf + par * 64 + b, s);
  }
}

// ---------------------------------------------------------------------------
// k_main: persistent decode loop, 3 grid barriers / step
// ---------------------------------------------------------------------------
__global__ __launch_bounds__(1024) void k_main(Ptrs P) {
  __shared__ float lds_g[16][16][16];   // 16 KB GEMM tile buffer
  __shared__ float lds_ctx[16][512];    // 32 KB ctx reduction
  __shared__ float lds_s[16];
  int bid = blockIdx.x, tid = threadIdx.x;
  int ep = 0;

  for (int t = 0; t < 300; ++t) {
    // -- Phase A: LSTM0(t) | hid(t-1) | attnnorm(t-1) | finalize(ctx t-1) ---
    if (bid < 32) lstm0_phase(bid, tid, t, P, lds_g);
    else if (bid < 48) { if (t > 0) hid_phase(bid, tid, t - 1, P, lds_g); }
    else if (bid < 64) { if (t > 0) attnnorm_phase(bid, tid, t - 1, P); }
    else if (bid < 66) { if (t > 0 && t < 299) finalize_phase(bid - 64, tid, t - 1, P); }
    gbar(P, ++ep);

    // -- Phase B: LSTM1(t) | logits(t-1) | zero sbuf[(t-1)&1] ---------------
    if (bid < 32) lstm1_phase(bid, tid, t, P, lds_g);
    else if (bid < 40) { if (t > 0) logits_phase(bid, tid, t - 1, P, false); }
    else if (bid == 40) { if (tid < 64) st_f32_sc(P.sbuf + ((t ^ 1) & 1) * 64 + tid, 0.f); }
    gbar(P, ++ep);

    // -- Phase C: fused attention sweep -------------------------------------
    sweep(bid, tid, t, P, lds_ctx, lds_s);
    gbar(P, ++ep);

    // -- step 298: need argmax(logits_298) as step-299 input ----------------
    if (t == 298) {
      if (bid >= 32 && bid < 48) hid_phase(bid, tid, 298, P, lds_g);
      else if (bid >= 64 && bid < 66) finalize_phase(bid - 64, tid, 298, P);
      gbar(P, ++ep);
      if (bid >= 32 && bid < 40) logits_phase(bid, tid, 298, P, true);
      gbar(P, ++ep);
    }
  }
  // tail: finalize(ctx 299) + hid(299) + attnnorm(299), then logits(299)
  if (bid >= 32 && bid < 48) hid_phase(bid, tid, 299, P, lds_g);
  else if (bid >= 48 && bid < 64) attnnorm_phase(bid, tid, 299, P);
  else if (bid >= 64 && bid < 66) finalize_phase(bid - 64, tid, 299, P);
  gbar(P, ++ep);
  if (bid >= 32 && bid < 40) logits_phase(bid, tid, 299, P, false);
}

// ---------------------------------------------------------------------------
extern "C" void kernel_launch(void* const* d_in, const int* in_sizes, int n_in,
                              void* d_out, int out_size, void* d_ws, size_t ws_size,
                              hipStream_t stream) {
  (void)in_sizes; (void)n_in; (void)out_size; (void)ws_size;
  Ptrs P;
  P.enc   = (const float*)d_in[0];
  P.elen  = (const int*)d_in[1];
  P.y     = (const int*)d_in[2];
  P.emb   = (const float*)d_in[3];
  P.Wih0  = (const float*)d_in[4];
  P.Whh0  = (const float*)d_in[5];
  P.bih0  = (const float*)d_in[6];
  P.bhh0  = (const float*)d_in[7];
  P.Wih1  = (const float*)d_in[8];
  P.Whh1  = (const float*)d_in[9];
  P.bih1  = (const float*)d_in[10];
  P.bhh1  = (const float*)d_in[11];
  P.Wq    = (const float*)d_in[12];
  P.Wk    = (const float*)d_in[13];
  P.Wv    = (const float*)d_in[14];
  P.Wout  = (const float*)d_in[15];
  P.bout  = (const float*)d_in[16];
  P.bchar = (const float*)d_in[17];
  P.out   = (float*)d_out;

  char* ws = (char*)d_ws;
  size_t o = 0;
  auto alloc = [&](size_t n) { char* p = ws + o; o = (o + n + 255) & ~(size_t)255; return p; };
  P.kv     = (unsigned short*)alloc(64000ull * 1024 * 2);   // 131 MB
  P.W0p    = (unsigned short*)alloc(2048ull * 1536 * 2);
  P.W1p    = (unsigned short*)alloc(2048ull * 1024 * 2);
  P.Wob    = (unsigned short*)alloc(512ull * 1024 * 2);
  P.WkvT   = (unsigned short*)alloc(1024ull * 512 * 2);
  P.embbf  = (unsigned short*)alloc(31ull * 512 * 2);
  P.b0p    = (float*)alloc(2048 * 4);
  P.b1p    = (float*)alloc(2048 * 4);
  P.h0b    = (unsigned short*)alloc(2ull * 64 * 512 * 2);
  P.h1b    = (unsigned short*)alloc(2ull * 64 * 512 * 2);
  P.hidb   = (unsigned short*)alloc(64ull * 512 * 2);
  P.embsel = (unsigned short*)alloc(64ull * 512 * 2);
  P.c0s    = (float*)alloc(64ull * 512 * 4);
  P.c1s    = (float*)alloc(64ull * 512 * 4);
  P.ctxa   = (float*)alloc(2ull * 64 * 512 * 4);
  P.ctxbf  = (unsigned short*)alloc(2ull * 64 * 512 * 2);
  P.ebuf   = (float*)alloc(2ull * 64 * 1024 * 4);
  P.sbuf   = (float*)alloc(2ull * 64 * 4);
  P.barArr = (int*)alloc(256 * 4);
  P.ctxflag= (int*)alloc(512 * 4);
  P.abortf = (int*)alloc(4);

  k_init<<<dim3(256), dim3(256), 0, stream>>>(P);
  k_prep<<<dim3(256), dim3(256), 0, stream>>>(P);
  k_kv<<<dim3(256), dim3(1024), 0, stream>>>(P);
  k_main<<<dim3(256), dim3(1024), 0, stream>>>(P);
}

// Round 4
// 30079.529 us; speedup vs baseline: 1.3958x; 1.3812x over previous
//
#include <hip/hip_runtime.h>

// ---------------------------------------------------------------------------
// Speller (LAS decoder) on MI355X — round 6: de-persistified.
// Rounds 3-5 falsified every intra-kernel theory (cache maintenance, flag
// contention, serial load chains): per-step time is pinned at ~135us across
// four different designs. Only invariant left: the persistent-kernel
// spin-barrier structure itself — unobservable from rocprof (one 40ms blob).
// Round 6: per-phase kernel launches (3/step, ~907 total, graph-sequenced).
//  * dispatch boundaries replace spin barriers (HW-sequenced, no spinning).
//  * ALL memory plain-cached again (inter-kernel coherence is free; L2/LLC
//    stay warm across same-device launches).
//  * per-phase rocprof rows -> next round sees exactly which phase costs.
// Phases per step t:
//   k_A: lstm0(t) | hid(t-1) | attnnorm(t-1)        (64 blocks)
//   k_B: lstm1(t) | logits(t-1) | zero ctxa/sbuf[t&1] (48 blocks)
//   k_C: fused attention sweep(t)                    (256 blocks)
// Step 298 extra: k_hid(298); k_logits(298, argmax) -> embsel.
// Tail: k_hid(299); k_attn(299); k_logits(299).
// ---------------------------------------------------------------------------

typedef __attribute__((ext_vector_type(8))) short s8bf;   // 8 bf16 (4 VGPRs)
typedef __attribute__((ext_vector_type(4))) float f32x4;

#define SCALE_E 0.044194173824159216f   // 1/sqrt(512)

struct Ptrs {
  const float* enc; const int* elen; const int* y;
  const float* emb;
  const float* Wih0; const float* Whh0; const float* bih0; const float* bhh0;
  const float* Wih1; const float* Whh1; const float* bih1; const float* bhh1;
  const float* Wq; const float* Wk; const float* Wv;
  const float* Wout; const float* bout; const float* bchar;
  unsigned short* kv;     // [64000][1024] bf16: keys2 (Wq folded) | vals
  unsigned short* W0p;    // [2048][1536] bf16, gate-permuted
  unsigned short* W1p;    // [2048][1024] bf16, gate-permuted
  unsigned short* Wob;    // [512][1024] bf16
  unsigned short* WkvT;   // [1024][512] bf16
  unsigned short* embbf;  // [31][512] bf16
  float* b0p; float* b1p; // [2048] permuted summed biases
  unsigned short* h0b;    // [2][64][512] bf16, parity t&1
  unsigned short* h1b;    // [2][64][512] bf16, parity t&1
  unsigned short* hidb;   // [64][512] bf16
  unsigned short* embsel; // [64][512] bf16
  float* c0s; float* c1s; // [64][512] fp32 cell states
  float* ctxa;            // [2][64][512] f32 unnormalized ctx accum
  float* ebuf;            // [2][64][1024] unnormalized exp(e) (tails stay 0)
  float* sbuf;            // [2][64] softmax denominators
  float* out;             // d_out: [64][300][31] logits then [64][300][1000] attn
};

__device__ __forceinline__ unsigned short f2bf(float f) {
  unsigned u = __float_as_uint(f);
  u += 0x7fffu + ((u >> 16) & 1u);          // RNE
  return (unsigned short)(u >> 16);
}
__device__ __forceinline__ float bf2f(unsigned short h) {
  return __uint_as_float(((unsigned)h) << 16);
}
__device__ __forceinline__ float sigm(float x) { return 1.f / (1.f + __expf(-x)); }

// ---------------------------------------------------------------------------
// k_init: zero states and accumulators (visible to later kernels at boundary)
// ---------------------------------------------------------------------------
__global__ void k_init(Ptrs P) {
  int g = blockIdx.x * 256 + threadIdx.x;            // 65536 threads
  for (int i = g; i < 32768; i += 65536) { P.c0s[i] = 0.f; P.c1s[i] = 0.f; }
  for (int i = g; i < 65536; i += 65536) {
    P.h0b[i] = 0; P.h1b[i] = 0; P.ctxa[i] = 0.f;
  }
  for (int i = g; i < 131072; i += 65536) P.ebuf[i] = 0.f;
  if (g < 128) P.sbuf[g] = 0.f;
}

// ---------------------------------------------------------------------------
// k_prep: bf16 weight conversion + gate permutation + Wk@Wq^T fold
// ---------------------------------------------------------------------------
__global__ void k_prep(Ptrs P) {
  int bid = blockIdx.x, tid = threadIdx.x;
  for (int ri = 0; ri < 8; ++ri) {
    int gp = bid * 8 + ri;
    int r = (gp & 3) * 512 + (gp >> 2);
    for (int k = tid; k < 1536; k += 256)
      P.W0p[(size_t)gp * 1536 + k] =
          f2bf(k < 1024 ? P.Wih0[(size_t)r * 1024 + k] : P.Whh0[(size_t)r * 512 + (k - 1024)]);
    for (int k = tid; k < 1024; k += 256)
      P.W1p[(size_t)gp * 1024 + k] =
          f2bf(k < 512 ? P.Wih1[(size_t)r * 512 + k] : P.Whh1[(size_t)r * 512 + (k - 512)]);
    if (tid == 0) {
      P.b0p[gp] = P.bih0[r] + P.bhh0[r];
      P.b1p[gp] = P.bih1[r] + P.bhh1[r];
    }
  }
  for (int ri = 0; ri < 2; ++ri) {
    int n = bid * 2 + ri;
    for (int k = tid; k < 1024; k += 256)
      P.Wob[(size_t)n * 1024 + k] = f2bf(P.Wout[(size_t)n * 1024 + k]);
  }
  {
    int g = bid * 256 + tid;
    if (g < 31 * 512) P.embbf[g] = f2bf(P.emb[g]);
  }
  for (int ri = 0; ri < 4; ++ri) {
    int n = bid * 4 + ri;
    if (n < 512) {
      const float* wq = P.Wq + (size_t)n * 512;
      for (int k = tid; k < 512; k += 256) {
        const float* wk = P.Wk + (size_t)k * 512;
        float s0 = 0.f, s1 = 0.f, s2 = 0.f, s3 = 0.f;
        for (int j = 0; j < 512; j += 4) {
          f32x4 a = *(const f32x4*)(wk + j);
          f32x4 b = *(const f32x4*)(wq + j);
          s0 = fmaf(a[0], b[0], s0); s1 = fmaf(a[1], b[1], s1);
          s2 = fmaf(a[2], b[2], s2); s3 = fmaf(a[3], b[3], s3);
        }
        P.WkvT[(size_t)n * 512 + k] = f2bf((s0 + s1) + (s2 + s3));
      }
    } else {
      for (int k = tid; k < 512; k += 256)
        P.WkvT[(size_t)n * 512 + k] = f2bf(P.Wv[(size_t)k * 512 + (n - 512)]);
    }
  }
}

// ---------------------------------------------------------------------------
// k_kv: kv[m][n] = enc[m][:] @ WkvT[n][:]  (M=64000, N=1024, K=512)
// ---------------------------------------------------------------------------
__global__ __launch_bounds__(1024) void k_kv(Ptrs P) {
  int bid = blockIdx.x, tid = threadIdx.x;
  int w = tid >> 6, ln = tid & 63;
  __shared__ unsigned short lds2[16][16][16];
  int mt = bid * 16 + w;
  bool valid = mt < 4000;
  s8bf afr[16];
  if (valid) {
    const float* ar = P.enc + (size_t)(mt * 16 + (ln & 15)) * 512 + ((ln >> 4) * 8);
    for (int ks = 0; ks < 16; ++ks) {
      f32x4 v0 = *(const f32x4*)(ar + ks * 32);
      f32x4 v1 = *(const f32x4*)(ar + ks * 32 + 4);
      s8bf a;
      a[0] = (short)f2bf(v0[0]); a[1] = (short)f2bf(v0[1]);
      a[2] = (short)f2bf(v0[2]); a[3] = (short)f2bf(v0[3]);
      a[4] = (short)f2bf(v1[0]); a[5] = (short)f2bf(v1[1]);
      a[6] = (short)f2bf(v1[2]); a[7] = (short)f2bf(v1[3]);
      afr[ks] = a;
    }
  }
  for (int nt = 0; nt < 64; ++nt) {
    if (valid) {
      f32x4 acc = {0.f, 0.f, 0.f, 0.f};
      const unsigned short* br = P.WkvT + (size_t)(nt * 16 + (ln & 15)) * 512 + ((ln >> 4) * 8);
      for (int ks = 0; ks < 16; ++ks) {
        s8bf b = *(const s8bf*)(br + ks * 32);
        acc = __builtin_amdgcn_mfma_f32_16x16x32_bf16(afr[ks], b, acc, 0, 0, 0);
      }
      for (int r = 0; r < 4; ++r)
        lds2[w][(ln >> 4) * 4 + r][ln & 15] = f2bf(acc[r]);
    }
    __syncthreads();
    if (valid && ln < 32) {
      int row = ln >> 1, half = ln & 1;
      s8bf v = *(const s8bf*)&lds2[w][row][half * 8];
      *(s8bf*)(P.kv + (size_t)(mt * 16 + row) * 1024 + nt * 16 + half * 8) = v;
    }
    __syncthreads();
  }
}

// ---------------------------------------------------------------------------
// Phase bodies (all plain cached loads/stores; coherence at kernel boundary)
// ---------------------------------------------------------------------------
// LSTM0: gates = [emb|ctx(t-1)|h0(t-1)] @ W0p^T; blocks 0..31
__device__ __forceinline__ void lstm0_phase(int bid, int tid, int t, const Ptrs& P,
                                            float (*lds_g)[16][16]) {
  int w = tid >> 6, ln = tid & 63;
  int mt = w & 3, nt = bid * 4 + (w >> 2);
  int brow = mt * 16 + (ln & 15), koff = (ln >> 4) * 8;
  int cur = t & 1, prv = cur ^ 1;
  const unsigned short* bp = P.W0p + (size_t)(nt * 16 + (ln & 15)) * 1536 + koff;
  const unsigned short* embrow;
  if (t == 299) {
    embrow = P.embsel + (size_t)brow * 512 + koff;
  } else {
    int sym = (t == 0) ? 0 : P.y[brow * 300 + t];
    embrow = P.embbf + (size_t)sym * 512 + koff;
  }
  f32x4 acc = {0.f, 0.f, 0.f, 0.f};
  for (int ks = 0; ks < 16; ++ks) {
    s8bf af = *(const s8bf*)(embrow + ks * 32);
    s8bf bf8 = *(const s8bf*)(bp + ks * 32);
    acc = __builtin_amdgcn_mfma_f32_16x16x32_bf16(af, bf8, acc, 0, 0, 0);
  }
  if (t > 0) {
    float inv = 1.f / P.sbuf[prv * 64 + brow];
    const float* cp = P.ctxa + prv * 32768 + (size_t)brow * 512 + koff;
    for (int ks = 0; ks < 16; ++ks) {
      f32x4 v0 = *(const f32x4*)(cp + ks * 32);
      f32x4 v1 = *(const f32x4*)(cp + ks * 32 + 4);
      s8bf af;
      af[0] = (short)f2bf(v0[0] * inv); af[1] = (short)f2bf(v0[1] * inv);
      af[2] = (short)f2bf(v0[2] * inv); af[3] = (short)f2bf(v0[3] * inv);
      af[4] = (short)f2bf(v1[0] * inv); af[5] = (short)f2bf(v1[1] * inv);
      af[6] = (short)f2bf(v1[2] * inv); af[7] = (short)f2bf(v1[3] * inv);
      s8bf bf8 = *(const s8bf*)(bp + 512 + ks * 32);
      acc = __builtin_amdgcn_mfma_f32_16x16x32_bf16(af, bf8, acc, 0, 0, 0);
    }
  }
  {
    const unsigned short* hp = P.h0b + prv * 32768 + (size_t)brow * 512 + koff;
    for (int ks = 0; ks < 16; ++ks) {
      s8bf af = *(const s8bf*)(hp + ks * 32);
      s8bf bf8 = *(const s8bf*)(bp + 1024 + ks * 32);
      acc = __builtin_amdgcn_mfma_f32_16x16x32_bf16(af, bf8, acc, 0, 0, 0);
    }
  }
  float bias = P.b0p[nt * 16 + (ln & 15)];
  for (int r = 0; r < 4; ++r)
    lds_g[w][(ln >> 4) * 4 + r][ln & 15] = acc[r] + bias;
  __syncthreads();
  int rb = ln >> 2, c = ln & 3;
  float gi = lds_g[w][rb][4 * c + 0];
  float gf = lds_g[w][rb][4 * c + 1];
  float gg = lds_g[w][rb][4 * c + 2];
  float go = lds_g[w][rb][4 * c + 3];
  int bb = mt * 16 + rb, d = nt * 4 + c;
  float co = P.c0s[bb * 512 + d];
  float cn = fmaf(sigm(gf), co, sigm(gi) * tanhf(gg));
  float h = sigm(go) * tanhf(cn);
  P.c0s[bb * 512 + d] = cn;
  P.h0b[cur * 32768 + bb * 512 + d] = f2bf(h);
}

// LSTM1: gates = [h0(t)|h1(t-1)] @ W1p^T; blocks 0..31
__device__ __forceinline__ void lstm1_phase(int bid, int tid, int t, const Ptrs& P,
                                            float (*lds_g)[16][16]) {
  int w = tid >> 6, ln = tid & 63;
  int mt = w & 3, nt = bid * 4 + (w >> 2);
  int brow = mt * 16 + (ln & 15), koff = (ln >> 4) * 8;
  int cur = t & 1, prv = cur ^ 1;
  const unsigned short* bp = P.W1p + (size_t)(nt * 16 + (ln & 15)) * 1024 + koff;
  const unsigned short* h0p = P.h0b + cur * 32768 + (size_t)brow * 512 + koff;
  const unsigned short* h1p = P.h1b + prv * 32768 + (size_t)brow * 512 + koff;
  f32x4 acc = {0.f, 0.f, 0.f, 0.f};
  for (int ks = 0; ks < 16; ++ks) {
    s8bf af = *(const s8bf*)(h0p + ks * 32);
    s8bf bf8 = *(const s8bf*)(bp + ks * 32);
    acc = __builtin_amdgcn_mfma_f32_16x16x32_bf16(af, bf8, acc, 0, 0, 0);
  }
  for (int ks = 0; ks < 16; ++ks) {
    s8bf af = *(const s8bf*)(h1p + ks * 32);
    s8bf bf8 = *(const s8bf*)(bp + 512 + ks * 32);
    acc = __builtin_amdgcn_mfma_f32_16x16x32_bf16(af, bf8, acc, 0, 0, 0);
  }
  float bias = P.b1p[nt * 16 + (ln & 15)];
  for (int r = 0; r < 4; ++r)
    lds_g[w][(ln >> 4) * 4 + r][ln & 15] = acc[r] + bias;
  __syncthreads();
  int rb = ln >> 2, c = ln & 3;
  float gi = lds_g[w][rb][4 * c + 0];
  float gf = lds_g[w][rb][4 * c + 1];
  float gg = lds_g[w][rb][4 * c + 2];
  float go = lds_g[w][rb][4 * c + 3];
  int bb = mt * 16 + rb, d = nt * 4 + c;
  float co = P.c1s[bb * 512 + d];
  float cn = fmaf(sigm(gf), co, sigm(gi) * tanhf(gg));
  float h = sigm(go) * tanhf(cn);
  P.c1s[bb * 512 + d] = cn;
  P.h1b[cur * 32768 + bb * 512 + d] = f2bf(h);
}

// hid(s) = relu([h1(s)|ctx(s)] @ Wout^T + bout); bid in [32,48)
__device__ __forceinline__ void hid_phase(int bid, int tid, int s, const Ptrs& P,
                                          float (*lds_g)[16][16]) {
  int w = tid >> 6, ln = tid & 63;
  int nl = w >> 3, kq = (w >> 2) & 1, mt = w & 3;
  int nt = (bid - 32) * 2 + nl;
  int brow = mt * 16 + (ln & 15), koff = (ln >> 4) * 8;
  int par = s & 1;
  const unsigned short* bp = P.Wob + (size_t)(nt * 16 + (ln & 15)) * 1024 + kq * 512 + koff;
  f32x4 acc = {0.f, 0.f, 0.f, 0.f};
  if (kq == 0) {
    const unsigned short* ap = P.h1b + par * 32768 + (size_t)brow * 512 + koff;
    for (int ks = 0; ks < 16; ++ks) {
      s8bf af = *(const s8bf*)(ap + ks * 32);
      s8bf bf8 = *(const s8bf*)(bp + ks * 32);
      acc = __builtin_amdgcn_mfma_f32_16x16x32_bf16(af, bf8, acc, 0, 0, 0);
    }
  } else {
    float inv = 1.f / P.sbuf[par * 64 + brow];
    const float* ap = P.ctxa + par * 32768 + (size_t)brow * 512 + koff;
    for (int ks = 0; ks < 16; ++ks) {
      f32x4 v0 = *(const f32x4*)(ap + ks * 32);
      f32x4 v1 = *(const f32x4*)(ap + ks * 32 + 4);
      s8bf af;
      af[0] = (short)f2bf(v0[0] * inv); af[1] = (short)f2bf(v0[1] * inv);
      af[2] = (short)f2bf(v0[2] * inv); af[3] = (short)f2bf(v0[3] * inv);
      af[4] = (short)f2bf(v1[0] * inv); af[5] = (short)f2bf(v1[1] * inv);
      af[6] = (short)f2bf(v1[2] * inv); af[7] = (short)f2bf(v1[3] * inv);
      s8bf bf8 = *(const s8bf*)(bp + ks * 32);
      acc = __builtin_amdgcn_mfma_f32_16x16x32_bf16(af, bf8, acc, 0, 0, 0);
    }
  }
  for (int r = 0; r < 4; ++r)
    lds_g[w][(ln >> 4) * 4 + r][ln & 15] = acc[r];
  __syncthreads();
  for (int r = 0; r < 2; ++r) {
    int idx = r * 1024 + tid;
    int tile = idx >> 8;                 // 0..7: nl2 = tile>>2, mt2 = tile&3
    int nl2 = tile >> 2, mt2 = tile & 3;
    int rb = (idx >> 4) & 15, cc = idx & 15;
    float hsum = lds_g[nl2 * 8 + mt2][rb][cc] + lds_g[nl2 * 8 + 4 + mt2][rb][cc];
    int ntg = (bid - 32) * 2 + nl2;
    hsum += P.bout[ntg * 16 + cc];
    hsum = fmaxf(hsum, 0.f);
    P.hidb[(size_t)(mt2 * 16 + rb) * 512 + ntg * 16 + cc] = f2bf(hsum);
  }
}

// logits(s) from hidb; bid in [32,40), waves 0..7 (one b per wave)
__device__ __forceinline__ void logits_phase(int bid, int tid, int s, const Ptrs& P,
                                             bool do_argmax) {
  int w = tid >> 6, ln = tid & 63;
  if (w >= 8) return;
  int b = (bid - 32) * 8 + w;
  float hv[8];
  s8bf hh = *(const s8bf*)(P.hidb + (size_t)b * 512 + ln * 8);
  for (int j = 0; j < 8; ++j) hv[j] = bf2f((unsigned short)hh[j]);
  float mx = -3.4e38f; int am = 0;
  for (int v = 0; v < 31; ++v) {
    s8bf ee = *(const s8bf*)(P.embbf + (size_t)v * 512 + ln * 8);
    float p = 0.f;
    for (int j = 0; j < 8; ++j) p = fmaf(bf2f((unsigned short)ee[j]), hv[j], p);
    for (int off = 32; off; off >>= 1) p += __shfl_down(p, off);
    if (ln == 0) {
      float lg = p + P.bchar[v];
      P.out[(size_t)b * 9300 + (size_t)s * 31 + v] = lg;
      if (lg > mx) { mx = lg; am = v; }
    }
  }
  if (do_argmax) {
    am = __shfl(am, 0);
    *(s8bf*)(P.embsel + (size_t)b * 512 + ln * 8) =
        *(const s8bf*)(P.embbf + (size_t)am * 512 + ln * 8);
  }
}

// attention-plot normalize+write for step s; bid in [48,64)
__device__ __forceinline__ void attnnorm_phase(int bid, int tid, int s, const Ptrs& P) {
  int idx = (bid - 48) * 1024 + tid;
  if (idx >= 16000) return;
  int b = idx / 250, r = idx - b * 250;
  int par = s & 1;
  float inv = 1.f / P.sbuf[par * 64 + b];
  f32x4 v = *(const f32x4*)(P.ebuf + par * 65536 + b * 1024 + r * 4);
  v[0] *= inv; v[1] *= inv; v[2] *= inv; v[3] *= inv;
  *(f32x4*)(P.out + 595200 + (size_t)b * 300000 + (size_t)s * 1000 + r * 4) = v;
}

// ---------------------------------------------------------------------------
// Per-phase kernels
// ---------------------------------------------------------------------------
__global__ __launch_bounds__(1024) void k_A(Ptrs P, int t, int do_hid) {
  __shared__ float lds_g[16][16][16];
  int bid = blockIdx.x, tid = threadIdx.x;
  if (bid < 32) lstm0_phase(bid, tid, t, P, lds_g);
  else if (bid < 48) { if (t > 0 && do_hid) hid_phase(bid, tid, t - 1, P, lds_g); }
  else { if (t > 0) attnnorm_phase(bid, tid, t - 1, P); }
}

__global__ __launch_bounds__(1024) void k_B(Ptrs P, int t, int do_logits) {
  __shared__ float lds_g[16][16][16];
  int bid = blockIdx.x, tid = threadIdx.x;
  if (bid < 32) lstm1_phase(bid, tid, t, P, lds_g);
  else if (bid < 40) { if (t > 0 && do_logits) logits_phase(bid, tid, t - 1, P, false); }
  else {
    int idx = (bid - 40) * 1024 + tid;                 // 0..8191
    f32x4 z = {0.f, 0.f, 0.f, 0.f};
    *(f32x4*)(P.ctxa + (t & 1) * 32768 + idx * 4) = z;
    if (bid == 40 && tid < 64) P.sbuf[(t & 1) * 64 + tid] = 0.f;
  }
}

// fused attention sweep over kv; 256 blocks
__global__ __launch_bounds__(1024) void k_C(Ptrs P, int t) {
  __shared__ float lds_ctx[16][512];
  __shared__ float lds_s[16];
  int bid = blockIdx.x, tid = threadIdx.x;
  int w = tid >> 6, ln = tid & 63;
  int b = bid >> 2, ch = bid & 3;
  int par = t & 1;
  int len = P.elen[b];
  int t0 = ch * 250;
  int lim = t0 + 250; if (len < lim) lim = len;
  float h1r[8];
  {
    s8bf hh = *(const s8bf*)(P.h1b + par * 32768 + (size_t)b * 512 + ln * 8);
    for (int j = 0; j < 8; ++j) h1r[j] = bf2f((unsigned short)hh[j]);
  }
  float acc[8] = {0.f, 0.f, 0.f, 0.f, 0.f, 0.f, 0.f, 0.f};
  float wsum = 0.f;
  float* eb = P.ebuf + par * 65536 + b * 1024;
  const unsigned short* kvb = P.kv + (size_t)b * 1000 * 1024;
  int tt = t0 + w;
  s8bf k0, v0, k1, v1;
  bool hv0 = tt < lim, hv1 = (tt + 16) < lim;
  if (hv0) {
    const unsigned short* r = kvb + (size_t)tt * 1024 + ln * 8;
    k0 = *(const s8bf*)r; v0 = *(const s8bf*)(r + 512);
  }
  if (hv1) {
    const unsigned short* r = kvb + (size_t)(tt + 16) * 1024 + ln * 8;
    k1 = *(const s8bf*)r; v1 = *(const s8bf*)(r + 512);
  }
  while (hv0) {
    s8bf k2, v2;
    bool hv2 = (tt + 32) < lim;
    if (hv2) {                                   // prefetch depth 2
      const unsigned short* r = kvb + (size_t)(tt + 32) * 1024 + ln * 8;
      k2 = *(const s8bf*)r; v2 = *(const s8bf*)(r + 512);
    }
    float p0 = 0.f, p1 = 0.f;
    for (int j = 0; j < 8; j += 2) {
      p0 = fmaf(bf2f((unsigned short)k0[j]), h1r[j], p0);
      p1 = fmaf(bf2f((unsigned short)k0[j + 1]), h1r[j + 1], p1);
    }
    float p = p0 + p1;
    p += __shfl_xor(p, 32); p += __shfl_xor(p, 16); p += __shfl_xor(p, 8);
    p += __shfl_xor(p, 4);  p += __shfl_xor(p, 2);  p += __shfl_xor(p, 1);
    float pe = __expf(p * SCALE_E);              // |e| small: no max-sub needed
    if (ln == 0) { eb[tt] = pe; wsum += pe; }
    for (int j = 0; j < 8; ++j)
      acc[j] = fmaf(bf2f((unsigned short)v0[j]), pe, acc[j]);
    k0 = k1; v0 = v1; hv0 = hv1;
    k1 = k2; v1 = v2; hv1 = hv2;
    tt += 16;
  }
  if (ln == 0) lds_s[w] = wsum;
  for (int j = 0; j < 8; ++j) lds_ctx[w][ln * 8 + j] = acc[j];
  __syncthreads();
  if (tid < 512) {
    float s = 0.f;
    for (int i = 0; i < 16; ++i) s += lds_ctx[i][tid];
    unsafeAtomicAdd(P.ctxa + par * 32768 + b * 512 + tid, s);
  }
  if (tid == 0) {
    float s = 0.f;
    for (int i = 0; i < 16; ++i) s += lds_s[i];
    unsafeAtomicAdd(P.sbuf + par * 64 + b, s);
  }
}

// standalone tail/extra kernels (reuse bodies via bid offset)
__global__ __launch_bounds__(1024) void k_hid(Ptrs P, int t) {
  __shared__ float lds_g[16][16][16];
  hid_phase(blockIdx.x + 32, threadIdx.x, t, P, lds_g);
}
__global__ __launch_bounds__(512) void k_logits(Ptrs P, int t, int do_argmax) {
  logits_phase(blockIdx.x + 32, threadIdx.x, t, P, do_argmax != 0);
}
__global__ __launch_bounds__(1024) void k_attn(Ptrs P, int t) {
  attnnorm_phase(blockIdx.x + 48, threadIdx.x, t, P);
}

// ---------------------------------------------------------------------------
extern "C" void kernel_launch(void* const* d_in, const int* in_sizes, int n_in,
                              void* d_out, int out_size, void* d_ws, size_t ws_size,
                              hipStream_t stream) {
  (void)in_sizes; (void)n_in; (void)out_size; (void)ws_size;
  Ptrs P;
  P.enc   = (const float*)d_in[0];
  P.elen  = (const int*)d_in[1];
  P.y     = (const int*)d_in[2];
  P.emb   = (const float*)d_in[3];
  P.Wih0  = (const float*)d_in[4];
  P.Whh0  = (const float*)d_in[5];
  P.bih0  = (const float*)d_in[6];
  P.bhh0  = (const float*)d_in[7];
  P.Wih1  = (const float*)d_in[8];
  P.Whh1  = (const float*)d_in[9];
  P.bih1  = (const float*)d_in[10];
  P.bhh1  = (const float*)d_in[11];
  P.Wq    = (const float*)d_in[12];
  P.Wk    = (const float*)d_in[13];
  P.Wv    = (const float*)d_in[14];
  P.Wout  = (const float*)d_in[15];
  P.bout  = (const float*)d_in[16];
  P.bchar = (const float*)d_in[17];
  P.out   = (float*)d_out;

  char* ws = (char*)d_ws;
  size_t o = 0;
  auto alloc = [&](size_t n) { char* p = ws + o; o = (o + n + 255) & ~(size_t)255; return p; };
  P.kv     = (unsigned short*)alloc(64000ull * 1024 * 2);   // 131 MB
  P.W0p    = (unsigned short*)alloc(2048ull * 1536 * 2);
  P.W1p    = (unsigned short*)alloc(2048ull * 1024 * 2);
  P.Wob    = (unsigned short*)alloc(512ull * 1024 * 2);
  P.WkvT   = (unsigned short*)alloc(1024ull * 512 * 2);
  P.embbf  = (unsigned short*)alloc(31ull * 512 * 2);
  P.b0p    = (float*)alloc(2048 * 4);
  P.b1p    = (float*)alloc(2048 * 4);
  P.h0b    = (unsigned short*)alloc(2ull * 64 * 512 * 2);
  P.h1b    = (unsigned short*)alloc(2ull * 64 * 512 * 2);
  P.hidb   = (unsigned short*)alloc(64ull * 512 * 2);
  P.embsel = (unsigned short*)alloc(64ull * 512 * 2);
  P.c0s    = (float*)alloc(64ull * 512 * 4);
  P.c1s    = (float*)alloc(64ull * 512 * 4);
  P.ctxa   = (float*)alloc(2ull * 64 * 512 * 4);
  P.ebuf   = (float*)alloc(2ull * 64 * 1024 * 4);
  P.sbuf   = (float*)alloc(2ull * 64 * 4);

  k_init<<<dim3(256), dim3(256), 0, stream>>>(P);
  k_prep<<<dim3(256), dim3(256), 0, stream>>>(P);
  k_kv<<<dim3(256), dim3(1024), 0, stream>>>(P);

  for (int t = 0; t < 300; ++t) {
    int last = (t == 299);
    k_A<<<dim3(64), dim3(1024), 0, stream>>>(P, t, last ? 0 : 1);
    k_B<<<dim3(48), dim3(1024), 0, stream>>>(P, t, last ? 0 : 1);
    k_C<<<dim3(256), dim3(1024), 0, stream>>>(P, t);
    if (t == 298) {
      k_hid<<<dim3(16), dim3(1024), 0, stream>>>(P, 298);
      k_logits<<<dim3(8), dim3(512), 0, stream>>>(P, 298, 1);
    }
  }
  k_hid<<<dim3(16), dim3(1024), 0, stream>>>(P, 299);
  k_attn<<<dim3(16), dim3(1024), 0, stream>>>(P, 299);
  k_logits<<<dim3(8), dim3(512), 0, stream>>>(P, 299, 0);
}

// Round 5
// 20849.323 us; speedup vs baseline: 2.0137x; 1.4427x over previous
//
#include <hip/hip_runtime.h>

// ---------------------------------------------------------------------------
// Speller (LAS decoder) on MI355X — round 7.
// Round-6 result: de-persistifying cut 41.5->30.1ms => sync-event cost
// (~35us each, any mechanism) dominates; ~100us/step over 3 dispatches.
// Round 7: 2 dispatches/step + balanced sweep.
//  * k_AB merges lstm0+lstm1: 64 blocks = 4 batch-groups x 16 gate-slices;
//    group-local flag sync (16 blocks/group, monotonic atomic counter);
//    h0 staged to LDS for lstm1. Weights slice->XCD aligned (L2-resident).
//  * k_C sweep rebalanced: plan[] computed on device assigns ~len-proportional
//    block counts per batch; worst block ~122 rows (was 250).
//  * riders (hid/attnnorm/zero | logits) unchanged, re-tiled to 512 threads.
//  * cross-dispatch = plain cached; same-dispatch h0 = sc atomics (r5-proven).
// ---------------------------------------------------------------------------

typedef __attribute__((ext_vector_type(8))) short s8bf;   // 8 bf16 (4 VGPRs)
typedef __attribute__((ext_vector_type(4))) float f32x4;

#define SCALE_E 0.044194173824159216f   // 1/sqrt(512)
#define SWEEP_SLOTS 352
#define POLL_CAP 65536

struct Ptrs {
  const float* enc; const int* elen; const int* y;
  const float* emb;
  const float* Wih0; const float* Whh0; const float* bih0; const float* bhh0;
  const float* Wih1; const float* Whh1; const float* bih1; const float* bhh1;
  const float* Wq; const float* Wk; const float* Wv;
  const float* Wout; const float* bout; const float* bchar;
  unsigned short* kv;     // [64000][1024] bf16: keys2 (Wq folded) | vals
  unsigned short* W0p;    // [2048][1536] bf16, gate-permuted (4d+gate)
  unsigned short* W1p;    // [2048][1024] bf16, gate-permuted
  unsigned short* Wob;    // [512][1024] bf16
  unsigned short* WkvT;   // [1024][512] bf16
  unsigned short* embbf;  // [31][512] bf16
  float* b0p; float* b1p; // [2048] permuted summed biases
  unsigned short* h0b;    // [2][64][512] bf16, parity t&1 (sc within k_AB)
  unsigned short* h1b;    // [2][64][512] bf16, parity t&1 (plain)
  unsigned short* hidb;   // [64][512] bf16
  unsigned short* embsel; // [64][512] bf16
  float* c0s; float* c1s; // [64][512] fp32 cell states
  float* ctxa;            // [2][64][512] f32 unnormalized ctx accum
  float* ebuf;            // [2][64][1024] unnormalized exp(e) (tails stay 0)
  float* sbuf;            // [2][64] softmax denominators
  int* plan;              // [65] prefix of per-batch sweep block counts
  int* flagA;             // [4*16] group flags (monotonic)
  float* out;             // d_out: [64][300][31] logits then [64][300][1000] attn
};

__device__ __forceinline__ unsigned short f2bf(float f) {
  unsigned u = __float_as_uint(f);
  u += 0x7fffu + ((u >> 16) & 1u);          // RNE
  return (unsigned short)(u >> 16);
}
__device__ __forceinline__ float bf2f(unsigned short h) {
  return __uint_as_float(((unsigned)h) << 16);
}
__device__ __forceinline__ float sigm(float x) { return 1.f / (1.f + __expf(-x)); }

// relaxed agent-scope helpers (same-dispatch cross-block comm only)
__device__ __forceinline__ void st_u32_sc(unsigned* p, unsigned v) {
  __hip_atomic_store(p, v, __ATOMIC_RELAXED, __HIP_MEMORY_SCOPE_AGENT);
}
__device__ __forceinline__ s8bf ld16_sc(const unsigned short* p) {
  union { unsigned long long u[2]; s8bf v; } w;
  w.u[0] = __hip_atomic_load((unsigned long long*)p, __ATOMIC_RELAXED,
                             __HIP_MEMORY_SCOPE_AGENT);
  w.u[1] = __hip_atomic_load((unsigned long long*)(p + 4), __ATOMIC_RELAXED,
                             __HIP_MEMORY_SCOPE_AGENT);
  return w.v;
}

// ---------------------------------------------------------------------------
__global__ void k_init(Ptrs P) {
  int g = blockIdx.x * 256 + threadIdx.x;            // 65536 threads
  for (int i = g; i < 32768; i += 65536) { P.c0s[i] = 0.f; P.c1s[i] = 0.f; }
  for (int i = g; i < 65536; i += 65536) {
    P.h0b[i] = 0; P.h1b[i] = 0; P.ctxa[i] = 0.f;
  }
  for (int i = g; i < 131072; i += 65536) P.ebuf[i] = 0.f;
  if (g < 128) P.sbuf[g] = 0.f;
  if (g < 64) P.flagA[g] = 0;
}

// ---------------------------------------------------------------------------
// k_prep: bf16 weight conversion + gate permutation + Wk@Wq^T fold + sweep plan
// ---------------------------------------------------------------------------
__global__ void k_prep(Ptrs P) {
  int bid = blockIdx.x, tid = threadIdx.x;
  for (int ri = 0; ri < 8; ++ri) {
    int gp = bid * 8 + ri;
    int r = (gp & 3) * 512 + (gp >> 2);
    for (int k = tid; k < 1536; k += 256)
      P.W0p[(size_t)gp * 1536 + k] =
          f2bf(k < 1024 ? P.Wih0[(size_t)r * 1024 + k] : P.Whh0[(size_t)r * 512 + (k - 1024)]);
    for (int k = tid; k < 1024; k += 256)
      P.W1p[(size_t)gp * 1024 + k] =
          f2bf(k < 512 ? P.Wih1[(size_t)r * 512 + k] : P.Whh1[(size_t)r * 512 + (k - 512)]);
    if (tid == 0) {
      P.b0p[gp] = P.bih0[r] + P.bhh0[r];
      P.b1p[gp] = P.bih1[r] + P.bhh1[r];
    }
  }
  for (int ri = 0; ri < 2; ++ri) {
    int n = bid * 2 + ri;
    for (int k = tid; k < 1024; k += 256)
      P.Wob[(size_t)n * 1024 + k] = f2bf(P.Wout[(size_t)n * 1024 + k]);
  }
  {
    int g = bid * 256 + tid;
    if (g < 31 * 512) P.embbf[g] = f2bf(P.emb[g]);
  }
  for (int ri = 0; ri < 4; ++ri) {
    int n = bid * 4 + ri;
    if (n < 512) {
      const float* wq = P.Wq + (size_t)n * 512;
      for (int k = tid; k < 512; k += 256) {
        const float* wk = P.Wk + (size_t)k * 512;
        float s0 = 0.f, s1 = 0.f, s2 = 0.f, s3 = 0.f;
        for (int j = 0; j < 512; j += 4) {
          f32x4 a = *(const f32x4*)(wk + j);
          f32x4 b = *(const f32x4*)(wq + j);
          s0 = fmaf(a[0], b[0], s0); s1 = fmaf(a[1], b[1], s1);
          s2 = fmaf(a[2], b[2], s2); s3 = fmaf(a[3], b[3], s3);
        }
        P.WkvT[(size_t)n * 512 + k] = f2bf((s0 + s1) + (s2 + s3));
      }
    } else {
      for (int k = tid; k < 512; k += 256)
        P.WkvT[(size_t)n * 512 + k] = f2bf(P.Wv[(size_t)k * 512 + (n - 512)]);
    }
  }
  // sweep plan: per-batch block counts proportional to len, prefix-summed
  if (bid == 0 && tid == 0) {
    int tot = 0;
    for (int b = 0; b < 64; ++b) {
      int l = P.elen[b]; if (l > 1000) l = 1000;
      tot += l;
    }
    int acc = 0;
    P.plan[0] = 0;
    for (int b = 0; b < 64; ++b) {
      int l = P.elen[b]; if (l > 1000) l = 1000;
      int nb = (int)(((long long)l * 288) / tot);
      if (nb < 1) nb = 1;
      acc += nb;
      P.plan[b + 1] = acc;                  // acc <= 288+64 <= SWEEP_SLOTS
    }
  }
}

// ---------------------------------------------------------------------------
// k_kv: kv[m][n] = enc[m][:] @ WkvT[n][:]  (M=64000, N=1024, K=512)
// ---------------------------------------------------------------------------
__global__ __launch_bounds__(1024) void k_kv(Ptrs P) {
  int bid = blockIdx.x, tid = threadIdx.x;
  int w = tid >> 6, ln = tid & 63;
  __shared__ unsigned short lds2[16][16][16];
  int mt = bid * 16 + w;
  bool valid = mt < 4000;
  s8bf afr[16];
  if (valid) {
    const float* ar = P.enc + (size_t)(mt * 16 + (ln & 15)) * 512 + ((ln >> 4) * 8);
    for (int ks = 0; ks < 16; ++ks) {
      f32x4 v0 = *(const f32x4*)(ar + ks * 32);
      f32x4 v1 = *(const f32x4*)(ar + ks * 32 + 4);
      s8bf a;
      a[0] = (short)f2bf(v0[0]); a[1] = (short)f2bf(v0[1]);
      a[2] = (short)f2bf(v0[2]); a[3] = (short)f2bf(v0[3]);
      a[4] = (short)f2bf(v1[0]); a[5] = (short)f2bf(v1[1]);
      a[6] = (short)f2bf(v1[2]); a[7] = (short)f2bf(v1[3]);
      afr[ks] = a;
    }
  }
  for (int nt = 0; nt < 64; ++nt) {
    if (valid) {
      f32x4 acc = {0.f, 0.f, 0.f, 0.f};
      const unsigned short* br = P.WkvT + (size_t)(nt * 16 + (ln & 15)) * 512 + ((ln >> 4) * 8);
      for (int ks = 0; ks < 16; ++ks) {
        s8bf b = *(const s8bf*)(br + ks * 32);
        acc = __builtin_amdgcn_mfma_f32_16x16x32_bf16(afr[ks], b, acc, 0, 0, 0);
      }
      for (int r = 0; r < 4; ++r)
        lds2[w][(ln >> 4) * 4 + r][ln & 15] = f2bf(acc[r]);
    }
    __syncthreads();
    if (valid && ln < 32) {
      int row = ln >> 1, half = ln & 1;
      s8bf v = *(const s8bf*)&lds2[w][row][half * 8];
      *(s8bf*)(P.kv + (size_t)(mt * 16 + row) * 1024 + nt * 16 + half * 8) = v;
    }
    __syncthreads();
  }
}

// ---------------------------------------------------------------------------
// rider bodies (512-thread blocks)
// ---------------------------------------------------------------------------
// hid(s): j = 0..31 (= nt), 8 waves: kq(2) x mt(4)
__device__ __forceinline__ void hid_phase(int j, int tid, int s, const Ptrs& P,
                                          float (*lds_g)[16][16]) {
  int w = tid >> 6, ln = tid & 63;
  int kq = w >> 2, mt = w & 3;
  int nt = j;
  int brow = mt * 16 + (ln & 15), koff = (ln >> 4) * 8;
  int par = s & 1;
  const unsigned short* bp = P.Wob + (size_t)(nt * 16 + (ln & 15)) * 1024 + kq * 512 + koff;
  f32x4 acc = {0.f, 0.f, 0.f, 0.f};
  if (kq == 0) {
    const unsigned short* ap = P.h1b + par * 32768 + (size_t)brow * 512 + koff;
    for (int ks = 0; ks < 16; ++ks) {
      s8bf af = *(const s8bf*)(ap + ks * 32);
      s8bf bf8 = *(const s8bf*)(bp + ks * 32);
      acc = __builtin_amdgcn_mfma_f32_16x16x32_bf16(af, bf8, acc, 0, 0, 0);
    }
  } else {
    float inv = 1.f / P.sbuf[par * 64 + brow];
    const float* ap = P.ctxa + par * 32768 + (size_t)brow * 512 + koff;
    for (int ks = 0; ks < 16; ++ks) {
      f32x4 v0 = *(const f32x4*)(ap + ks * 32);
      f32x4 v1 = *(const f32x4*)(ap + ks * 32 + 4);
      s8bf af;
      af[0] = (short)f2bf(v0[0] * inv); af[1] = (short)f2bf(v0[1] * inv);
      af[2] = (short)f2bf(v0[2] * inv); af[3] = (short)f2bf(v0[3] * inv);
      af[4] = (short)f2bf(v1[0] * inv); af[5] = (short)f2bf(v1[1] * inv);
      af[6] = (short)f2bf(v1[2] * inv); af[7] = (short)f2bf(v1[3] * inv);
      s8bf bf8 = *(const s8bf*)(bp + ks * 32);
      acc = __builtin_amdgcn_mfma_f32_16x16x32_bf16(af, bf8, acc, 0, 0, 0);
    }
  }
  for (int r = 0; r < 4; ++r)
    lds_g[w][(ln >> 4) * 4 + r][ln & 15] = acc[r];
  __syncthreads();
  for (int r = 0; r < 2; ++r) {
    int idx = r * 512 + tid;               // 0..1023: mt2(4) x rb(16) x cc(16)
    int mt2 = idx >> 8, rb = (idx >> 4) & 15, cc = idx & 15;
    float hsum = lds_g[mt2][rb][cc] + lds_g[4 + mt2][rb][cc];
    hsum += P.bout[nt * 16 + cc];
    hsum = fmaxf(hsum, 0.f);
    P.hidb[(size_t)(mt2 * 16 + rb) * 512 + nt * 16 + cc] = f2bf(hsum);
  }
}

// logits(s): lb = 0..7, 8 waves (one b per wave)
__device__ __forceinline__ void logits_phase(int lb, int tid, int s, const Ptrs& P,
                                             bool do_argmax) {
  int w = tid >> 6, ln = tid & 63;
  if (w >= 8) return;
  int b = lb * 8 + w;
  float hv[8];
  s8bf hh = *(const s8bf*)(P.hidb + (size_t)b * 512 + ln * 8);
  for (int j = 0; j < 8; ++j) hv[j] = bf2f((unsigned short)hh[j]);
  float mx = -3.4e38f; int am = 0;
  for (int v = 0; v < 31; ++v) {
    s8bf ee = *(const s8bf*)(P.embbf + (size_t)v * 512 + ln * 8);
    float p = 0.f;
    for (int j = 0; j < 8; ++j) p = fmaf(bf2f((unsigned short)ee[j]), hv[j], p);
    for (int off = 32; off; off >>= 1) p += __shfl_down(p, off);
    if (ln == 0) {
      float lg = p + P.bchar[v];
      P.out[(size_t)b * 9300 + (size_t)s * 31 + v] = lg;
      if (lg > mx) { mx = lg; am = v; }
    }
  }
  if (do_argmax) {
    am = __shfl(am, 0);
    *(s8bf*)(P.embsel + (size_t)b * 512 + ln * 8) =
        *(const s8bf*)(P.embbf + (size_t)am * 512 + ln * 8);
  }
}

// attnnorm(s): j = 0..31
__device__ __forceinline__ void attnnorm_phase(int j, int tid, int s, const Ptrs& P) {
  int idx = j * 512 + tid;
  if (idx >= 16000) return;
  int b = idx / 250, r = idx - b * 250;
  int par = s & 1;
  float inv = 1.f / P.sbuf[par * 64 + b];
  f32x4 v = *(const f32x4*)(P.ebuf + par * 65536 + b * 1024 + r * 4);
  v[0] *= inv; v[1] *= inv; v[2] *= inv; v[3] *= inv;
  *(f32x4*)(P.out + 595200 + (size_t)b * 300000 + (size_t)s * 1000 + r * 4) = v;
}

// ---------------------------------------------------------------------------
// k_AB: lstm0 -> group sync -> lstm1  (blocks 0..63: group g = bid>>4, slice
// s = bid&15); riders: hid(t-1) [64,96), attnnorm(t-1) [96,128), zero [128,144)
// ---------------------------------------------------------------------------
__global__ __launch_bounds__(512) void k_AB(Ptrs P, int t, int do_hid) {
  __shared__ float lds_g[8][16][16];            // 8 KB
  __shared__ unsigned short lds_h0[16][520];    // 16.25 KB (pad 8 vs bank conflicts)
  int bid = blockIdx.x, tid = threadIdx.x;

  if (bid < 64) {
    int g = bid >> 4, s = bid & 15;
    int w = tid >> 6, ln = tid & 63;
    int nt = s * 8 + w;                         // row-tile 0..127
    int brow = g * 16 + (ln & 15);              // batch
    int koff = (ln >> 4) * 8;
    int cur = t & 1, prv = cur ^ 1;

    // ---- lstm0: gates = [emb|ctx(t-1)|h0(t-1)] @ W0p^T ----
    const unsigned short* bp = P.W0p + (size_t)(nt * 16 + (ln & 15)) * 1536 + koff;
    f32x4 acc = {0.f, 0.f, 0.f, 0.f};
    {
      const unsigned short* embrow;
      if (t == 299) {
        embrow = P.embsel + (size_t)brow * 512 + koff;
      } else {
        int sym = (t == 0) ? 0 : P.y[brow * 300 + t];
        embrow = P.embbf + (size_t)sym * 512 + koff;
      }
      for (int ks = 0; ks < 16; ++ks) {
        s8bf af = *(const s8bf*)(embrow + ks * 32);
        s8bf bf8 = *(const s8bf*)(bp + ks * 32);
        acc = __builtin_amdgcn_mfma_f32_16x16x32_bf16(af, bf8, acc, 0, 0, 0);
      }
    }
    if (t > 0) {
      float inv = 1.f / P.sbuf[prv * 64 + brow];
      const float* cp = P.ctxa + prv * 32768 + (size_t)brow * 512 + koff;
      for (int ks = 0; ks < 16; ++ks) {
        f32x4 v0 = *(const f32x4*)(cp + ks * 32);
        f32x4 v1 = *(const f32x4*)(cp + ks * 32 + 4);
        s8bf af;
        af[0] = (short)f2bf(v0[0] * inv); af[1] = (short)f2bf(v0[1] * inv);
        af[2] = (short)f2bf(v0[2] * inv); af[3] = (short)f2bf(v0[3] * inv);
        af[4] = (short)f2bf(v1[0] * inv); af[5] = (short)f2bf(v1[1] * inv);
        af[6] = (short)f2bf(v1[2] * inv); af[7] = (short)f2bf(v1[3] * inv);
        s8bf bf8 = *(const s8bf*)(bp + 512 + ks * 32);
        acc = __builtin_amdgcn_mfma_f32_16x16x32_bf16(af, bf8, acc, 0, 0, 0);
      }
    }
    {
      const unsigned short* hp = P.h0b + prv * 32768 + (size_t)brow * 512 + koff;
      for (int ks = 0; ks < 16; ++ks) {
        s8bf af = *(const s8bf*)(hp + ks * 32);
        s8bf bf8 = *(const s8bf*)(bp + 1024 + ks * 32);
        acc = __builtin_amdgcn_mfma_f32_16x16x32_bf16(af, bf8, acc, 0, 0, 0);
      }
    }
    {
      float bias = P.b0p[nt * 16 + (ln & 15)];
      for (int r = 0; r < 4; ++r)
        lds_g[w][(ln >> 4) * 4 + r][ln & 15] = acc[r] + bias;
    }
    __syncthreads();
    {
      int tile = tid >> 6, rb = (tid >> 2) & 15, c = tid & 3;
      float gi = lds_g[tile][rb][4 * c + 0];
      float gf = lds_g[tile][rb][4 * c + 1];
      float gg = lds_g[tile][rb][4 * c + 2];
      float go = lds_g[tile][rb][4 * c + 3];
      int bb = g * 16 + rb, d = (s * 8 + tile) * 4 + c;
      float co = P.c0s[bb * 512 + d];
      float cn = fmaf(sigm(gf), co, sigm(gi) * tanhf(gg));
      float h = sigm(go) * tanhf(cn);
      P.c0s[bb * 512 + d] = cn;
      unsigned short hb = f2bf(h);
      int pr = __shfl_xor((int)(unsigned)hb, 1);
      if ((tid & 1) == 0)
        st_u32_sc((unsigned*)(P.h0b + cur * 32768 + bb * 512 + d),
                  ((unsigned)hb) | ((unsigned)pr << 16));
    }
    __syncthreads();   // drains all waves' h0 sc stores (vmcnt before barrier)

    // ---- group sync: 16 slice-blocks of group g ----
    if (tid == 0) {
      __hip_atomic_fetch_add(P.flagA + g * 16, 1, __ATOMIC_RELAXED,
                             __HIP_MEMORY_SCOPE_AGENT);
      int target = 16 * (t + 1);
      int gc = 0;
      while (__hip_atomic_load(P.flagA + g * 16, __ATOMIC_RELAXED,
                               __HIP_MEMORY_SCOPE_AGENT) < target) {
        if (++gc > POLL_CAP) break;
        __builtin_amdgcn_s_sleep(1);
      }
    }
    __syncthreads();

    // ---- stage h0[group] (16 x 512 bf16) into LDS ----
    {
      int bb2 = tid >> 5;                 // 0..15
      int c0 = (tid & 31) * 16;           // 0..496
      const unsigned short* src = P.h0b + cur * 32768 + (size_t)(g * 16 + bb2) * 512 + c0;
      s8bf v0 = ld16_sc(src);
      s8bf v1 = ld16_sc(src + 8);
      *(s8bf*)&lds_h0[bb2][c0] = v0;
      *(s8bf*)&lds_h0[bb2][c0 + 8] = v1;
    }
    __syncthreads();

    // ---- lstm1: gates = [h0(t)|h1(t-1)] @ W1p^T ----
    const unsigned short* bp1 = P.W1p + (size_t)(nt * 16 + (ln & 15)) * 1024 + koff;
    f32x4 acc1 = {0.f, 0.f, 0.f, 0.f};
    for (int ks = 0; ks < 16; ++ks) {
      s8bf af = *(const s8bf*)&lds_h0[ln & 15][koff + ks * 32];
      s8bf bf8 = *(const s8bf*)(bp1 + ks * 32);
      acc1 = __builtin_amdgcn_mfma_f32_16x16x32_bf16(af, bf8, acc1, 0, 0, 0);
    }
    {
      const unsigned short* h1p = P.h1b + prv * 32768 + (size_t)brow * 512 + koff;
      for (int ks = 0; ks < 16; ++ks) {
        s8bf af = *(const s8bf*)(h1p + ks * 32);
        s8bf bf8 = *(const s8bf*)(bp1 + 512 + ks * 32);
        acc1 = __builtin_amdgcn_mfma_f32_16x16x32_bf16(af, bf8, acc1, 0, 0, 0);
      }
    }
    {
      float bias = P.b1p[nt * 16 + (ln & 15)];
      for (int r = 0; r < 4; ++r)
        lds_g[w][(ln >> 4) * 4 + r][ln & 15] = acc1[r] + bias;
    }
    __syncthreads();
    {
      int tile = tid >> 6, rb = (tid >> 2) & 15, c = tid & 3;
      float gi = lds_g[tile][rb][4 * c + 0];
      float gf = lds_g[tile][rb][4 * c + 1];
      float gg = lds_g[tile][rb][4 * c + 2];
      float go = lds_g[tile][rb][4 * c + 3];
      int bb = g * 16 + rb, d = (s * 8 + tile) * 4 + c;
      float co = P.c1s[bb * 512 + d];
      float cn = fmaf(sigm(gf), co, sigm(gi) * tanhf(gg));
      float h = sigm(go) * tanhf(cn);
      P.c1s[bb * 512 + d] = cn;
      unsigned short hb = f2bf(h);
      int pr = __shfl_xor((int)(unsigned)hb, 1);
      if ((tid & 1) == 0)
        *(unsigned*)(P.h1b + cur * 32768 + bb * 512 + d) =
            ((unsigned)hb) | ((unsigned)pr << 16);   // plain: next-dispatch readers
    }
  } else if (bid < 96) {
    if (t > 0 && do_hid) hid_phase(bid - 64, tid, t - 1, P, lds_g);
  } else if (bid < 128) {
    if (t > 0) attnnorm_phase(bid - 96, tid, t - 1, P);
  } else {
    int idx = (bid - 128) * 512 + tid;               // 0..8191
    f32x4 z = {0.f, 0.f, 0.f, 0.f};
    *(f32x4*)(P.ctxa + (t & 1) * 32768 + idx * 4) = z;
    if (bid == 128 && tid < 64) P.sbuf[(t & 1) * 64 + tid] = 0.f;
  }
}

// ---------------------------------------------------------------------------
// k_C: balanced sweep (slots 0..SWEEP_SLOTS) + logits(t-1) rider
// ---------------------------------------------------------------------------
__global__ __launch_bounds__(1024) void k_C(Ptrs P, int t, int do_logits) {
  __shared__ float lds_ctx[16][512];
  __shared__ float lds_s[16];
  __shared__ int lplan[65];
  int bid = blockIdx.x, tid = threadIdx.x;
  if (bid >= SWEEP_SLOTS) {
    if (do_logits) logits_phase(bid - SWEEP_SLOTS, tid, t - 1, P, false);
    return;
  }
  if (tid < 65) lplan[tid] = P.plan[tid];
  __syncthreads();
  if (bid >= lplan[64]) return;
  int lo = 0, hi = 64;
  while (lo + 1 < hi) { int mid = (lo + hi) >> 1; if (bid >= lplan[mid]) lo = mid; else hi = mid; }
  int b = lo;
  int nb = lplan[b + 1] - lplan[b];
  int ci = bid - lplan[b];
  int len = P.elen[b]; if (len > 1000) len = 1000;
  int per = (len + nb - 1) / nb;
  int t0 = ci * per;
  int lim = t0 + per; if (lim > len) lim = len;
  if (t0 >= lim) return;

  int w = tid >> 6, ln = tid & 63;
  int par = t & 1;
  float h1r[8];
  {
    s8bf hh = *(const s8bf*)(P.h1b + par * 32768 + (size_t)b * 512 + ln * 8);
    for (int j = 0; j < 8; ++j) h1r[j] = bf2f((unsigned short)hh[j]);
  }
  float acc[8] = {0.f, 0.f, 0.f, 0.f, 0.f, 0.f, 0.f, 0.f};
  float wsum = 0.f;
  float* eb = P.ebuf + par * 65536 + b * 1024;
  const unsigned short* kvb = P.kv + (size_t)b * 1000 * 1024;
  int tt = t0 + w;
  s8bf k0, v0, k1, v1;
  bool hv0 = tt < lim, hv1 = (tt + 16) < lim;
  if (hv0) {
    const unsigned short* r = kvb + (size_t)tt * 1024 + ln * 8;
    k0 = *(const s8bf*)r; v0 = *(const s8bf*)(r + 512);
  }
  if (hv1) {
    const unsigned short* r = kvb + (size_t)(tt + 16) * 1024 + ln * 8;
    k1 = *(const s8bf*)r; v1 = *(const s8bf*)(r + 512);
  }
  while (hv0) {
    s8bf k2, v2;
    bool hv2 = (tt + 32) < lim;
    if (hv2) {                                   // prefetch depth 2
      const unsigned short* r = kvb + (size_t)(tt + 32) * 1024 + ln * 8;
      k2 = *(const s8bf*)r; v2 = *(const s8bf*)(r + 512);
    }
    float p0 = 0.f, p1 = 0.f;
    for (int j = 0; j < 8; j += 2) {
      p0 = fmaf(bf2f((unsigned short)k0[j]), h1r[j], p0);
      p1 = fmaf(bf2f((unsigned short)k0[j + 1]), h1r[j + 1], p1);
    }
    float p = p0 + p1;
    p += __shfl_xor(p, 32); p += __shfl_xor(p, 16); p += __shfl_xor(p, 8);
    p += __shfl_xor(p, 4);  p += __shfl_xor(p, 2);  p += __shfl_xor(p, 1);
    float pe = __expf(p * SCALE_E);              // |e| small: no max-sub needed
    if (ln == 0) { eb[tt] = pe; wsum += pe; }
    for (int j = 0; j < 8; ++j)
      acc[j] = fmaf(bf2f((unsigned short)v0[j]), pe, acc[j]);
    k0 = k1; v0 = v1; hv0 = hv1;
    k1 = k2; v1 = v2; hv1 = hv2;
    tt += 16;
  }
  if (ln == 0) lds_s[w] = wsum;
  for (int j = 0; j < 8; ++j) lds_ctx[w][ln * 8 + j] = acc[j];
  __syncthreads();
  if (tid < 512) {
    float s = 0.f;
    for (int i = 0; i < 16; ++i) s += lds_ctx[i][tid];
    unsafeAtomicAdd(P.ctxa + par * 32768 + b * 512 + tid, s);
  }
  if (tid == 0) {
    float s = 0.f;
    for (int i = 0; i < 16; ++i) s += lds_s[i];
    unsafeAtomicAdd(P.sbuf + par * 64 + b, s);
  }
}

// standalone tail/extra kernels
__global__ __launch_bounds__(512) void k_hid(Ptrs P, int t) {
  __shared__ float lds_g[8][16][16];
  hid_phase(blockIdx.x, threadIdx.x, t, P, lds_g);
}
__global__ __launch_bounds__(512) void k_logits(Ptrs P, int t, int do_argmax) {
  logits_phase(blockIdx.x, threadIdx.x, t, P, do_argmax != 0);
}
__global__ __launch_bounds__(512) void k_attn(Ptrs P, int t) {
  attnnorm_phase(blockIdx.x, threadIdx.x, t, P);
}

// ---------------------------------------------------------------------------
extern "C" void kernel_launch(void* const* d_in, const int* in_sizes, int n_in,
                              void* d_out, int out_size, void* d_ws, size_t ws_size,
                              hipStream_t stream) {
  (void)in_sizes; (void)n_in; (void)out_size; (void)ws_size;
  Ptrs P;
  P.enc   = (const float*)d_in[0];
  P.elen  = (const int*)d_in[1];
  P.y     = (const int*)d_in[2];
  P.emb   = (const float*)d_in[3];
  P.Wih0  = (const float*)d_in[4];
  P.Whh0  = (const float*)d_in[5];
  P.bih0  = (const float*)d_in[6];
  P.bhh0  = (const float*)d_in[7];
  P.Wih1  = (const float*)d_in[8];
  P.Whh1  = (const float*)d_in[9];
  P.bih1  = (const float*)d_in[10];
  P.bhh1  = (const float*)d_in[11];
  P.Wq    = (const float*)d_in[12];
  P.Wk    = (const float*)d_in[13];
  P.Wv    = (const float*)d_in[14];
  P.Wout  = (const float*)d_in[15];
  P.bout  = (const float*)d_in[16];
  P.bchar = (const float*)d_in[17];
  P.out   = (float*)d_out;

  char* ws = (char*)d_ws;
  size_t o = 0;
  auto alloc = [&](size_t n) { char* p = ws + o; o = (o + n + 255) & ~(size_t)255; return p; };
  P.kv     = (unsigned short*)alloc(64000ull * 1024 * 2);   // 131 MB
  P.W0p    = (unsigned short*)alloc(2048ull * 1536 * 2);
  P.W1p    = (unsigned short*)alloc(2048ull * 1024 * 2);
  P.Wob    = (unsigned short*)alloc(512ull * 1024 * 2);
  P.WkvT   = (unsigned short*)alloc(1024ull * 512 * 2);
  P.embbf  = (unsigned short*)alloc(31ull * 512 * 2);
  P.b0p    = (float*)alloc(2048 * 4);
  P.b1p    = (float*)alloc(2048 * 4);
  P.h0b    = (unsigned short*)alloc(2ull * 64 * 512 * 2);
  P.h1b    = (unsigned short*)alloc(2ull * 64 * 512 * 2);
  P.hidb   = (unsigned short*)alloc(64ull * 512 * 2);
  P.embsel = (unsigned short*)alloc(64ull * 512 * 2);
  P.c0s    = (float*)alloc(64ull * 512 * 4);
  P.c1s    = (float*)alloc(64ull * 512 * 4);
  P.ctxa   = (float*)alloc(2ull * 64 * 512 * 4);
  P.ebuf   = (float*)alloc(2ull * 64 * 1024 * 4);
  P.sbuf   = (float*)alloc(2ull * 64 * 4);
  P.plan   = (int*)alloc(65 * 4);
  P.flagA  = (int*)alloc(64 * 4);

  k_init<<<dim3(256), dim3(256), 0, stream>>>(P);
  k_prep<<<dim3(256), dim3(256), 0, stream>>>(P);
  k_kv<<<dim3(256), dim3(1024), 0, stream>>>(P);

  for (int t = 0; t < 300; ++t) {
    k_AB<<<dim3(144), dim3(512), 0, stream>>>(P, t, (t == 299) ? 0 : 1);
    k_C<<<dim3(SWEEP_SLOTS + 8), dim3(1024), 0, stream>>>(
        P, t, (t > 0 && t != 299) ? 1 : 0);
    if (t == 298) {
      k_hid<<<dim3(32), dim3(512), 0, stream>>>(P, 298);
      k_logits<<<dim3(8), dim3(512), 0, stream>>>(P, 298, 1);
    }
  }
  k_hid<<<dim3(32), dim3(512), 0, stream>>>(P, 299);
  k_attn<<<dim3(32), dim3(512), 0, stream>>>(P, 299);
  k_logits<<<dim3(8), dim3(512), 0, stream>>>(P, 299, 0);
}

// Round 6
// 18024.387 us; speedup vs baseline: 2.3293x; 1.1567x over previous
//
#include <hip/hip_runtime.h>

// ---------------------------------------------------------------------------
// Speller (LAS decoder) on MI355X — round 8: one dispatch per step.
// Evidence: per-step cost ~= 33-35us x (number of serialized sync events);
// work rides nearly free (r6: 3 disp=100us/step; r7: 2 disp=69.5us/step).
// Round 8 merges everything into k_step (512 blocks x 512 thr, all
// co-resident):
//   bid 0..63   : lstm0 -> flagL(group) -> lstm1 -> zero+h1 -> flagH(group)
//   bid 64..95  : hid(t-1) rider -> flagHid
//   bid 96..127 : attnnorm(t-1) rider
//   bid 128..135: logits(t-1) rider (polls flagHid)
//   bid 136..511: balanced sweep slots (poll flagH of their batch's group)
// Same-dispatch cross-block data: relaxed agent-scope (sc) accesses
// (r5-proven). Cross-dispatch: plain cached (r6/r7-proven).
// Zeroing of ctxa/sbuf moved into lstm blocks (sc stores) before flagH.
// Deadlock-safe: launch_bounds(512,4) => VGPR<=128, LDS 24.3KB => >=2
// blocks/CU => all 512 blocks resident. Watchdog caps on every poll.
// ---------------------------------------------------------------------------

typedef __attribute__((ext_vector_type(8))) short s8bf;   // 8 bf16 (4 VGPRs)
typedef __attribute__((ext_vector_type(4))) float f32x4;

#define SCALE_E 0.044194173824159216f   // 1/sqrt(512)
#define SWEEP_SLOTS 376
#define POLL_CAP (1 << 19)

struct Ptrs {
  const float* enc; const int* elen; const int* y;
  const float* emb;
  const float* Wih0; const float* Whh0; const float* bih0; const float* bhh0;
  const float* Wih1; const float* Whh1; const float* bih1; const float* bhh1;
  const float* Wq; const float* Wk; const float* Wv;
  const float* Wout; const float* bout; const float* bchar;
  unsigned short* kv;     // [64000][1024] bf16: keys2 (Wq folded) | vals
  unsigned short* W0p;    // [2048][1536] bf16, gate-permuted (4d+gate)
  unsigned short* W1p;    // [2048][1024] bf16, gate-permuted
  unsigned short* Wob;    // [512][1024] bf16
  unsigned short* WkvT;   // [1024][512] bf16
  unsigned short* embbf;  // [31][512] bf16
  float* b0p; float* b1p; // [2048] permuted summed biases
  unsigned short* h0b;    // [2][64][512] bf16, parity t&1 (sc)
  unsigned short* h1b;    // [2][64][512] bf16, parity t&1 (sc)
  unsigned short* hidb;   // [64][512] bf16 (sc)
  unsigned short* embsel; // [64][512] bf16
  float* c0s; float* c1s; // [64][512] fp32 cell states (block-private)
  float* ctxa;            // [2][64][512] f32 unnormalized ctx accum
  float* ebuf;            // [2][64][1024] unnormalized exp(e) (tails stay 0)
  float* sbuf;            // [2][64] softmax denominators
  int* plan;              // [65] prefix of per-batch sweep block counts
  int* flagL;             // [4*16] lstm0->lstm1 group flags (monotonic)
  int* flagH;             // [4*16] lstm1/zero->sweep group flags (monotonic)
  int* flagHid;           // [16] hid->logits counter (monotonic)
  float* out;             // d_out: [64][300][31] logits then [64][300][1000] attn
};

__device__ __forceinline__ unsigned short f2bf(float f) {
  unsigned u = __float_as_uint(f);
  u += 0x7fffu + ((u >> 16) & 1u);          // RNE
  return (unsigned short)(u >> 16);
}
__device__ __forceinline__ float bf2f(unsigned short h) {
  return __uint_as_float(((unsigned)h) << 16);
}
__device__ __forceinline__ float sigm(float x) { return 1.f / (1.f + __expf(-x)); }

// relaxed agent-scope helpers (same-dispatch cross-block comm)
__device__ __forceinline__ void st_u32_sc(unsigned* p, unsigned v) {
  __hip_atomic_store(p, v, __ATOMIC_RELAXED, __HIP_MEMORY_SCOPE_AGENT);
}
__device__ __forceinline__ void st_f32_sc(float* p, float v) {
  __hip_atomic_store(p, v, __ATOMIC_RELAXED, __HIP_MEMORY_SCOPE_AGENT);
}
__device__ __forceinline__ s8bf ld16_sc(const unsigned short* p) {
  union { unsigned long long u[2]; s8bf v; } w;
  w.u[0] = __hip_atomic_load((unsigned long long*)p, __ATOMIC_RELAXED,
                             __HIP_MEMORY_SCOPE_AGENT);
  w.u[1] = __hip_atomic_load((unsigned long long*)(p + 4), __ATOMIC_RELAXED,
                             __HIP_MEMORY_SCOPE_AGENT);
  return w.v;
}
__device__ __forceinline__ void pollge(const int* p, int need) {
  int g = 0;
  while (__hip_atomic_load((int*)p, __ATOMIC_RELAXED, __HIP_MEMORY_SCOPE_AGENT) < need) {
    if (++g > POLL_CAP) break;
    if (g < 16) __builtin_amdgcn_s_sleep(1);
    else        __builtin_amdgcn_s_sleep(8);
  }
}

// ---------------------------------------------------------------------------
__global__ void k_init(Ptrs P) {
  int g = blockIdx.x * 256 + threadIdx.x;            // 65536 threads
  for (int i = g; i < 32768; i += 65536) { P.c0s[i] = 0.f; P.c1s[i] = 0.f; }
  for (int i = g; i < 65536; i += 65536) {
    P.h0b[i] = 0; P.h1b[i] = 0; P.ctxa[i] = 0.f;
  }
  for (int i = g; i < 131072; i += 65536) P.ebuf[i] = 0.f;
  if (g < 128) P.sbuf[g] = 0.f;
  if (g < 64) { P.flagL[g] = 0; P.flagH[g] = 0; }
  if (g < 16) P.flagHid[g] = 0;
}

// ---------------------------------------------------------------------------
// k_prep: bf16 weight conversion + gate permutation + Wk@Wq^T fold + sweep plan
// ---------------------------------------------------------------------------
__global__ void k_prep(Ptrs P) {
  int bid = blockIdx.x, tid = threadIdx.x;
  for (int ri = 0; ri < 8; ++ri) {
    int gp = bid * 8 + ri;
    int r = (gp & 3) * 512 + (gp >> 2);
    for (int k = tid; k < 1536; k += 256)
      P.W0p[(size_t)gp * 1536 + k] =
          f2bf(k < 1024 ? P.Wih0[(size_t)r * 1024 + k] : P.Whh0[(size_t)r * 512 + (k - 1024)]);
    for (int k = tid; k < 1024; k += 256)
      P.W1p[(size_t)gp * 1024 + k] =
          f2bf(k < 512 ? P.Wih1[(size_t)r * 512 + k] : P.Whh1[(size_t)r * 512 + (k - 512)]);
    if (tid == 0) {
      P.b0p[gp] = P.bih0[r] + P.bhh0[r];
      P.b1p[gp] = P.bih1[r] + P.bhh1[r];
    }
  }
  for (int ri = 0; ri < 2; ++ri) {
    int n = bid * 2 + ri;
    for (int k = tid; k < 1024; k += 256)
      P.Wob[(size_t)n * 1024 + k] = f2bf(P.Wout[(size_t)n * 1024 + k]);
  }
  {
    int g = bid * 256 + tid;
    if (g < 31 * 512) P.embbf[g] = f2bf(P.emb[g]);
  }
  for (int ri = 0; ri < 4; ++ri) {
    int n = bid * 4 + ri;
    if (n < 512) {
      const float* wq = P.Wq + (size_t)n * 512;
      for (int k = tid; k < 512; k += 256) {
        const float* wk = P.Wk + (size_t)k * 512;
        float s0 = 0.f, s1 = 0.f, s2 = 0.f, s3 = 0.f;
        for (int j = 0; j < 512; j += 4) {
          f32x4 a = *(const f32x4*)(wk + j);
          f32x4 b = *(const f32x4*)(wq + j);
          s0 = fmaf(a[0], b[0], s0); s1 = fmaf(a[1], b[1], s1);
          s2 = fmaf(a[2], b[2], s2); s3 = fmaf(a[3], b[3], s3);
        }
        P.WkvT[(size_t)n * 512 + k] = f2bf((s0 + s1) + (s2 + s3));
      }
    } else {
      for (int k = tid; k < 512; k += 256)
        P.WkvT[(size_t)n * 512 + k] = f2bf(P.Wv[(size_t)k * 512 + (n - 512)]);
    }
  }
  // sweep plan: per-batch block counts proportional to len, prefix-summed
  if (bid == 0 && tid == 0) {
    int tot = 0;
    for (int b = 0; b < 64; ++b) {
      int l = P.elen[b]; if (l > 1000) l = 1000;
      tot += l;
    }
    int acc = 0;
    P.plan[0] = 0;
    for (int b = 0; b < 64; ++b) {
      int l = P.elen[b]; if (l > 1000) l = 1000;
      int nb = (int)(((long long)l * 312) / tot);
      if (nb < 1) nb = 1;
      acc += nb;
      P.plan[b + 1] = acc;                  // acc <= 312+64 <= SWEEP_SLOTS
    }
  }
}

// ---------------------------------------------------------------------------
// k_kv: kv[m][n] = enc[m][:] @ WkvT[n][:]  (M=64000, N=1024, K=512)
// ---------------------------------------------------------------------------
__global__ __launch_bounds__(1024) void k_kv(Ptrs P) {
  int bid = blockIdx.x, tid = threadIdx.x;
  int w = tid >> 6, ln = tid & 63;
  __shared__ unsigned short lds2[16][16][16];
  int mt = bid * 16 + w;
  bool valid = mt < 4000;
  s8bf afr[16];
  if (valid) {
    const float* ar = P.enc + (size_t)(mt * 16 + (ln & 15)) * 512 + ((ln >> 4) * 8);
    for (int ks = 0; ks < 16; ++ks) {
      f32x4 v0 = *(const f32x4*)(ar + ks * 32);
      f32x4 v1 = *(const f32x4*)(ar + ks * 32 + 4);
      s8bf a;
      a[0] = (short)f2bf(v0[0]); a[1] = (short)f2bf(v0[1]);
      a[2] = (short)f2bf(v0[2]); a[3] = (short)f2bf(v0[3]);
      a[4] = (short)f2bf(v1[0]); a[5] = (short)f2bf(v1[1]);
      a[6] = (short)f2bf(v1[2]); a[7] = (short)f2bf(v1[3]);
      afr[ks] = a;
    }
  }
  for (int nt = 0; nt < 64; ++nt) {
    if (valid) {
      f32x4 acc = {0.f, 0.f, 0.f, 0.f};
      const unsigned short* br = P.WkvT + (size_t)(nt * 16 + (ln & 15)) * 512 + ((ln >> 4) * 8);
      for (int ks = 0; ks < 16; ++ks) {
        s8bf b = *(const s8bf*)(br + ks * 32);
        acc = __builtin_amdgcn_mfma_f32_16x16x32_bf16(afr[ks], b, acc, 0, 0, 0);
      }
      for (int r = 0; r < 4; ++r)
        lds2[w][(ln >> 4) * 4 + r][ln & 15] = f2bf(acc[r]);
    }
    __syncthreads();
    if (valid && ln < 32) {
      int row = ln >> 1, half = ln & 1;
      s8bf v = *(const s8bf*)&lds2[w][row][half * 8];
      *(s8bf*)(P.kv + (size_t)(mt * 16 + row) * 1024 + nt * 16 + half * 8) = v;
    }
    __syncthreads();
  }
}

// ---------------------------------------------------------------------------
// phase bodies
// ---------------------------------------------------------------------------
// hid(s): j = 0..31 (= nt), 8 waves: kq(2) x mt(4); sc stores to hidb
__device__ __forceinline__ void hid_phase(int j, int tid, int s, const Ptrs& P,
                                          float (*lds_g)[16][16]) {
  int w = tid >> 6, ln = tid & 63;
  int kq = w >> 2, mt = w & 3;
  int nt = j;
  int brow = mt * 16 + (ln & 15), koff = (ln >> 4) * 8;
  int par = s & 1;
  const unsigned short* bp = P.Wob + (size_t)(nt * 16 + (ln & 15)) * 1024 + kq * 512 + koff;
  f32x4 acc = {0.f, 0.f, 0.f, 0.f};
  if (kq == 0) {
    const unsigned short* ap = P.h1b + par * 32768 + (size_t)brow * 512 + koff;
    for (int ks = 0; ks < 16; ++ks) {
      s8bf af = *(const s8bf*)(ap + ks * 32);
      s8bf bf8 = *(const s8bf*)(bp + ks * 32);
      acc = __builtin_amdgcn_mfma_f32_16x16x32_bf16(af, bf8, acc, 0, 0, 0);
    }
  } else {
    float inv = 1.f / P.sbuf[par * 64 + brow];
    const float* ap = P.ctxa + par * 32768 + (size_t)brow * 512 + koff;
    for (int ks = 0; ks < 16; ++ks) {
      f32x4 v0 = *(const f32x4*)(ap + ks * 32);
      f32x4 v1 = *(const f32x4*)(ap + ks * 32 + 4);
      s8bf af;
      af[0] = (short)f2bf(v0[0] * inv); af[1] = (short)f2bf(v0[1] * inv);
      af[2] = (short)f2bf(v0[2] * inv); af[3] = (short)f2bf(v0[3] * inv);
      af[4] = (short)f2bf(v1[0] * inv); af[5] = (short)f2bf(v1[1] * inv);
      af[6] = (short)f2bf(v1[2] * inv); af[7] = (short)f2bf(v1[3] * inv);
      s8bf bf8 = *(const s8bf*)(bp + ks * 32);
      acc = __builtin_amdgcn_mfma_f32_16x16x32_bf16(af, bf8, acc, 0, 0, 0);
    }
  }
  for (int r = 0; r < 4; ++r)
    lds_g[w][(ln >> 4) * 4 + r][ln & 15] = acc[r];
  __syncthreads();
  for (int r = 0; r < 2; ++r) {
    int idx = r * 512 + tid;               // 0..1023: mt2(4) x rb(16) x cc(16)
    int mt2 = idx >> 8, rb = (idx >> 4) & 15, cc = idx & 15;
    float hsum = lds_g[mt2][rb][cc] + lds_g[4 + mt2][rb][cc];
    hsum += P.bout[nt * 16 + cc];
    hsum = fmaxf(hsum, 0.f);
    unsigned short hb = f2bf(hsum);
    int pr = __shfl_xor((int)(unsigned)hb, 1);
    if ((tid & 1) == 0)
      st_u32_sc((unsigned*)(P.hidb + (size_t)(mt2 * 16 + rb) * 512 + nt * 16 + cc),
                ((unsigned)hb) | ((unsigned)pr << 16));
  }
}

// logits(s): lb = 0..7, 8 waves (one b per wave); sc reads of hidb
__device__ __forceinline__ void logits_phase(int lb, int tid, int s, const Ptrs& P,
                                             bool do_argmax) {
  int w = tid >> 6, ln = tid & 63;
  if (w >= 8) return;
  int b = lb * 8 + w;
  float hv[8];
  s8bf hh = ld16_sc(P.hidb + (size_t)b * 512 + ln * 8);
  for (int j = 0; j < 8; ++j) hv[j] = bf2f((unsigned short)hh[j]);
  float mx = -3.4e38f; int am = 0;
  for (int v = 0; v < 31; ++v) {
    s8bf ee = *(const s8bf*)(P.embbf + (size_t)v * 512 + ln * 8);
    float p = 0.f;
    for (int j = 0; j < 8; ++j) p = fmaf(bf2f((unsigned short)ee[j]), hv[j], p);
    for (int off = 32; off; off >>= 1) p += __shfl_down(p, off);
    if (ln == 0) {
      float lg = p + P.bchar[v];
      P.out[(size_t)b * 9300 + (size_t)s * 31 + v] = lg;
      if (lg > mx) { mx = lg; am = v; }
    }
  }
  if (do_argmax) {
    am = __shfl(am, 0);
    *(s8bf*)(P.embsel + (size_t)b * 512 + ln * 8) =
        *(const s8bf*)(P.embbf + (size_t)am * 512 + ln * 8);
  }
}

// attnnorm(s): j = 0..31 (reads only prev-dispatch data)
__device__ __forceinline__ void attnnorm_phase(int j, int tid, int s, const Ptrs& P) {
  int idx = j * 512 + tid;
  if (idx >= 16000) return;
  int b = idx / 250, r = idx - b * 250;
  int par = s & 1;
  float inv = 1.f / P.sbuf[par * 64 + b];
  f32x4 v = *(const f32x4*)(P.ebuf + par * 65536 + b * 1024 + r * 4);
  v[0] *= inv; v[1] *= inv; v[2] *= inv; v[3] *= inv;
  *(f32x4*)(P.out + 595200 + (size_t)b * 300000 + (size_t)s * 1000 + r * 4) = v;
}

// ---------------------------------------------------------------------------
// k_step: one dispatch = one decode step
// ---------------------------------------------------------------------------
__global__ __launch_bounds__(512, 4) void k_step(Ptrs P, int t, int do_hid,
                                                 int do_logits) {
  __shared__ __align__(16) char smem[24832];
  int bid = blockIdx.x, tid = threadIdx.x;

  if (bid < 64) {
    // ---- lstm role: group g, slice s ----
    float (*lds_g)[16][16] = (float (*)[16][16])smem;
    unsigned short (*lds_h0)[520] = (unsigned short (*)[520])(smem + 8192);
    int g = bid >> 4, s = bid & 15;
    int w = tid >> 6, ln = tid & 63;
    int nt = s * 8 + w;                         // row-tile 0..127
    int brow = g * 16 + (ln & 15);              // batch
    int koff = (ln >> 4) * 8;
    int cur = t & 1, prv = cur ^ 1;

    // lstm0: gates = [emb|ctx(t-1)|h0(t-1)] @ W0p^T
    const unsigned short* bp = P.W0p + (size_t)(nt * 16 + (ln & 15)) * 1536 + koff;
    f32x4 acc = {0.f, 0.f, 0.f, 0.f};
    {
      const unsigned short* embrow;
      if (t == 299) {
        embrow = P.embsel + (size_t)brow * 512 + koff;
      } else {
        int sym = (t == 0) ? 0 : P.y[brow * 300 + t];
        embrow = P.embbf + (size_t)sym * 512 + koff;
      }
      for (int ks = 0; ks < 16; ++ks) {
        s8bf af = *(const s8bf*)(embrow + ks * 32);
        s8bf bf8 = *(const s8bf*)(bp + ks * 32);
        acc = __builtin_amdgcn_mfma_f32_16x16x32_bf16(af, bf8, acc, 0, 0, 0);
      }
    }
    if (t > 0) {
      float inv = 1.f / P.sbuf[prv * 64 + brow];
      const float* cp = P.ctxa + prv * 32768 + (size_t)brow * 512 + koff;
      for (int ks = 0; ks < 16; ++ks) {
        f32x4 v0 = *(const f32x4*)(cp + ks * 32);
        f32x4 v1 = *(const f32x4*)(cp + ks * 32 + 4);
        s8bf af;
        af[0] = (short)f2bf(v0[0] * inv); af[1] = (short)f2bf(v0[1] * inv);
        af[2] = (short)f2bf(v0[2] * inv); af[3] = (short)f2bf(v0[3] * inv);
        af[4] = (short)f2bf(v1[0] * inv); af[5] = (short)f2bf(v1[1] * inv);
        af[6] = (short)f2bf(v1[2] * inv); af[7] = (short)f2bf(v1[3] * inv);
        s8bf bf8 = *(const s8bf*)(bp + 512 + ks * 32);
        acc = __builtin_amdgcn_mfma_f32_16x16x32_bf16(af, bf8, acc, 0, 0, 0);
      }
    }
    {
      const unsigned short* hp = P.h0b + prv * 32768 + (size_t)brow * 512 + koff;
      for (int ks = 0; ks < 16; ++ks) {
        s8bf af = *(const s8bf*)(hp + ks * 32);
        s8bf bf8 = *(const s8bf*)(bp + 1024 + ks * 32);
        acc = __builtin_amdgcn_mfma_f32_16x16x32_bf16(af, bf8, acc, 0, 0, 0);
      }
    }
    {
      float bias = P.b0p[nt * 16 + (ln & 15)];
      for (int r = 0; r < 4; ++r)
        lds_g[w][(ln >> 4) * 4 + r][ln & 15] = acc[r] + bias;
    }
    __syncthreads();
    {
      int tile = tid >> 6, rb = (tid >> 2) & 15, c = tid & 3;
      float gi = lds_g[tile][rb][4 * c + 0];
      float gf = lds_g[tile][rb][4 * c + 1];
      float gg = lds_g[tile][rb][4 * c + 2];
      float go = lds_g[tile][rb][4 * c + 3];
      int bb = g * 16 + rb, d = (s * 8 + tile) * 4 + c;
      float co = P.c0s[bb * 512 + d];
      float cn = fmaf(sigm(gf), co, sigm(gi) * tanhf(gg));
      float h = sigm(go) * tanhf(cn);
      P.c0s[bb * 512 + d] = cn;
      unsigned short hb = f2bf(h);
      int pr = __shfl_xor((int)(unsigned)hb, 1);
      if ((tid & 1) == 0)
        st_u32_sc((unsigned*)(P.h0b + cur * 32768 + bb * 512 + d),
                  ((unsigned)hb) | ((unsigned)pr << 16));
    }
    // zero ctxa[cur] for my batch (bz) + sbuf[cur] (block s==0)
    {
      int bz = g * 16 + s;
      st_f32_sc(P.ctxa + cur * 32768 + bz * 512 + tid, 0.f);
      if (s == 0 && tid < 16) st_f32_sc(P.sbuf + cur * 64 + g * 16 + tid, 0.f);
    }
    __syncthreads();   // drains h0 sc stores + zeros (waitcnt before barrier)

    // group sync: h0 ready across the 16 slice-blocks of group g
    if (tid == 0) {
      __hip_atomic_fetch_add(P.flagL + g * 16, 1, __ATOMIC_RELAXED,
                             __HIP_MEMORY_SCOPE_AGENT);
      pollge(P.flagL + g * 16, 16 * (t + 1));
    }
    __syncthreads();

    // stage h0[group] (16 x 512 bf16) into LDS
    {
      int bb2 = tid >> 5;                 // 0..15
      int c0 = (tid & 31) * 16;           // 0..496
      const unsigned short* src = P.h0b + cur * 32768 + (size_t)(g * 16 + bb2) * 512 + c0;
      s8bf v0 = ld16_sc(src);
      s8bf v1 = ld16_sc(src + 8);
      *(s8bf*)&lds_h0[bb2][c0] = v0;
      *(s8bf*)&lds_h0[bb2][c0 + 8] = v1;
    }
    __syncthreads();

    // lstm1: gates = [h0(t)|h1(t-1)] @ W1p^T
    const unsigned short* bp1 = P.W1p + (size_t)(nt * 16 + (ln & 15)) * 1024 + koff;
    f32x4 acc1 = {0.f, 0.f, 0.f, 0.f};
    for (int ks = 0; ks < 16; ++ks) {
      s8bf af = *(const s8bf*)&lds_h0[ln & 15][koff + ks * 32];
      s8bf bf8 = *(const s8bf*)(bp1 + ks * 32);
      acc1 = __builtin_amdgcn_mfma_f32_16x16x32_bf16(af, bf8, acc1, 0, 0, 0);
    }
    {
      const unsigned short* h1p = P.h1b + prv * 32768 + (size_t)brow * 512 + koff;
      for (int ks = 0; ks < 16; ++ks) {
        s8bf af = *(const s8bf*)(h1p + ks * 32);
        s8bf bf8 = *(const s8bf*)(bp1 + 512 + ks * 32);
        acc1 = __builtin_amdgcn_mfma_f32_16x16x32_bf16(af, bf8, acc1, 0, 0, 0);
      }
    }
    {
      float bias = P.b1p[nt * 16 + (ln & 15)];
      for (int r = 0; r < 4; ++r)
        lds_g[w][(ln >> 4) * 4 + r][ln & 15] = acc1[r] + bias;
    }
    __syncthreads();
    {
      int tile = tid >> 6, rb = (tid >> 2) & 15, c = tid & 3;
      float gi = lds_g[tile][rb][4 * c + 0];
      float gf = lds_g[tile][rb][4 * c + 1];
      float gg = lds_g[tile][rb][4 * c + 2];
      float go = lds_g[tile][rb][4 * c + 3];
      int bb = g * 16 + rb, d = (s * 8 + tile) * 4 + c;
      float co = P.c1s[bb * 512 + d];
      float cn = fmaf(sigm(gf), co, sigm(gi) * tanhf(gg));
      float h = sigm(go) * tanhf(cn);
      P.c1s[bb * 512 + d] = cn;
      unsigned short hb = f2bf(h);
      int pr = __shfl_xor((int)(unsigned)hb, 1);
      if ((tid & 1) == 0)
        st_u32_sc((unsigned*)(P.h1b + cur * 32768 + bb * 512 + d),
                  ((unsigned)hb) | ((unsigned)pr << 16));
    }
    __syncthreads();   // drains h1 sc stores
    if (tid == 0)
      __hip_atomic_fetch_add(P.flagH + g * 16, 1, __ATOMIC_RELAXED,
                             __HIP_MEMORY_SCOPE_AGENT);

  } else if (bid < 96) {
    // ---- hid(t-1) rider ----
    if (t > 0 && do_hid) {
      hid_phase(bid - 64, tid, t - 1, P, (float (*)[16][16])smem);
      __syncthreads();   // drains hidb sc stores
      if (tid == 0)
        __hip_atomic_fetch_add(P.flagHid, 1, __ATOMIC_RELAXED,
                               __HIP_MEMORY_SCOPE_AGENT);
    }
  } else if (bid < 128) {
    // ---- attnnorm(t-1) rider ----
    if (t > 0) attnnorm_phase(bid - 96, tid, t - 1, P);
  } else if (bid < 136) {
    // ---- logits(t-1) rider ----
    if (t > 0 && do_logits) {
      if (tid == 0) pollge(P.flagHid, 32 * t);
      __syncthreads();
      logits_phase(bid - 128, tid, t - 1, P, false);
    }
  } else {
    // ---- sweep role ----
    float (*lds_ctx)[512] = (float (*)[512])smem;
    float* lds_s = (float*)(smem + 16384);
    int* lplan = (int*)(smem + 16448);
    if (tid < 65) lplan[tid] = P.plan[tid];
    __syncthreads();
    int slot = bid - 136;
    if (slot >= lplan[64]) return;
    int lo = 0, hi = 64;
    while (lo + 1 < hi) { int mid = (lo + hi) >> 1; if (slot >= lplan[mid]) lo = mid; else hi = mid; }
    int b = lo;
    int nb = lplan[b + 1] - lplan[b];
    int ci = slot - lplan[b];
    int len = P.elen[b]; if (len > 1000) len = 1000;
    int per = (len + nb - 1) / nb;
    int t0 = ci * per;
    int lim = t0 + per; if (lim > len) lim = len;
    if (t0 >= lim) return;

    // wait for h1(t) + zeroed ctxa/sbuf of this batch's group
    if (tid == 0) pollge(P.flagH + (b >> 4) * 16, 16 * (t + 1));
    __syncthreads();

    int w = tid >> 6, ln = tid & 63;
    int par = t & 1;
    float h1r[8];
    {
      s8bf hh = ld16_sc(P.h1b + par * 32768 + (size_t)b * 512 + ln * 8);
      for (int j = 0; j < 8; ++j) h1r[j] = bf2f((unsigned short)hh[j]);
    }
    float acc[8] = {0.f, 0.f, 0.f, 0.f, 0.f, 0.f, 0.f, 0.f};
    float wsum = 0.f;
    float* eb = P.ebuf + par * 65536 + b * 1024;
    const unsigned short* kvb = P.kv + (size_t)b * 1000 * 1024;
    int tt = t0 + w;
    s8bf k0, v0, k1, v1;
    bool hv0 = tt < lim, hv1 = (tt + 8) < lim;
    if (hv0) {
      const unsigned short* r = kvb + (size_t)tt * 1024 + ln * 8;
      k0 = *(const s8bf*)r; v0 = *(const s8bf*)(r + 512);
    }
    if (hv1) {
      const unsigned short* r = kvb + (size_t)(tt + 8) * 1024 + ln * 8;
      k1 = *(const s8bf*)r; v1 = *(const s8bf*)(r + 512);
    }
    while (hv0) {
      s8bf k2, v2;
      bool hv2 = (tt + 16) < lim;
      if (hv2) {                                 // prefetch depth 2
        const unsigned short* r = kvb + (size_t)(tt + 16) * 1024 + ln * 8;
        k2 = *(const s8bf*)r; v2 = *(const s8bf*)(r + 512);
      }
      float p0 = 0.f, p1 = 0.f;
      for (int j = 0; j < 8; j += 2) {
        p0 = fmaf(bf2f((unsigned short)k0[j]), h1r[j], p0);
        p1 = fmaf(bf2f((unsigned short)k0[j + 1]), h1r[j + 1], p1);
      }
      float p = p0 + p1;
      p += __shfl_xor(p, 32); p += __shfl_xor(p, 16); p += __shfl_xor(p, 8);
      p += __shfl_xor(p, 4);  p += __shfl_xor(p, 2);  p += __shfl_xor(p, 1);
      float pe = __expf(p * SCALE_E);            // |e| small: no max-sub needed
      if (ln == 0) { eb[tt] = pe; wsum += pe; }
      for (int j = 0; j < 8; ++j)
        acc[j] = fmaf(bf2f((unsigned short)v0[j]), pe, acc[j]);
      k0 = k1; v0 = v1; hv0 = hv1;
      k1 = k2; v1 = v2; hv1 = hv2;
      tt += 8;
    }
    if (ln == 0) lds_s[w] = wsum;
    for (int j = 0; j < 8; ++j) lds_ctx[w][ln * 8 + j] = acc[j];
    __syncthreads();
    {
      float ssum = 0.f;
      for (int i = 0; i < 8; ++i) ssum += lds_ctx[i][tid];
      unsafeAtomicAdd(P.ctxa + par * 32768 + b * 512 + tid, ssum);
    }
    if (tid == 0) {
      float ssum = 0.f;
      for (int i = 0; i < 8; ++i) ssum += lds_s[i];
      unsafeAtomicAdd(P.sbuf + par * 64 + b, ssum);
    }
  }
}

// standalone tail/extra kernels
__global__ __launch_bounds__(512) void k_hid(Ptrs P, int t) {
  __shared__ float lds_g[8][16][16];
  hid_phase(blockIdx.x, threadIdx.x, t, P, lds_g);
}
__global__ __launch_bounds__(512) void k_logits(Ptrs P, int t, int do_argmax) {
  logits_phase(blockIdx.x, threadIdx.x, t, P, do_argmax != 0);
}
__global__ __launch_bounds__(512) void k_attn(Ptrs P, int t) {
  attnnorm_phase(blockIdx.x, threadIdx.x, t, P);
}

// ---------------------------------------------------------------------------
extern "C" void kernel_launch(void* const* d_in, const int* in_sizes, int n_in,
                              void* d_out, int out_size, void* d_ws, size_t ws_size,
                              hipStream_t stream) {
  (void)in_sizes; (void)n_in; (void)out_size; (void)ws_size;
  Ptrs P;
  P.enc   = (const float*)d_in[0];
  P.elen  = (const int*)d_in[1];
  P.y     = (const int*)d_in[2];
  P.emb   = (const float*)d_in[3];
  P.Wih0  = (const float*)d_in[4];
  P.Whh0  = (const float*)d_in[5];
  P.bih0  = (const float*)d_in[6];
  P.bhh0  = (const float*)d_in[7];
  P.Wih1  = (const float*)d_in[8];
  P.Whh1  = (const float*)d_in[9];
  P.bih1  = (const float*)d_in[10];
  P.bhh1  = (const float*)d_in[11];
  P.Wq    = (const float*)d_in[12];
  P.Wk    = (const float*)d_in[13];
  P.Wv    = (const float*)d_in[14];
  P.Wout  = (const float*)d_in[15];
  P.bout  = (const float*)d_in[16];
  P.bchar = (const float*)d_in[17];
  P.out   = (float*)d_out;

  char* ws = (char*)d_ws;
  size_t o = 0;
  auto alloc = [&](size_t n) { char* p = ws + o; o = (o + n + 255) & ~(size_t)255; return p; };
  P.kv     = (unsigned short*)alloc(64000ull * 1024 * 2);   // 131 MB
  P.W0p    = (unsigned short*)alloc(2048ull * 1536 * 2);
  P.W1p    = (unsigned short*)alloc(2048ull * 1024 * 2);
  P.Wob    = (unsigned short*)alloc(512ull * 1024 * 2);
  P.WkvT   = (unsigned short*)alloc(1024ull * 512 * 2);
  P.embbf  = (unsigned short*)alloc(31ull * 512 * 2);
  P.b0p    = (float*)alloc(2048 * 4);
  P.b1p    = (float*)alloc(2048 * 4);
  P.h0b    = (unsigned short*)alloc(2ull * 64 * 512 * 2);
  P.h1b    = (unsigned short*)alloc(2ull * 64 * 512 * 2);
  P.hidb   = (unsigned short*)alloc(64ull * 512 * 2);
  P.embsel = (unsigned short*)alloc(64ull * 512 * 2);
  P.c0s    = (float*)alloc(64ull * 512 * 4);
  P.c1s    = (float*)alloc(64ull * 512 * 4);
  P.ctxa   = (float*)alloc(2ull * 64 * 512 * 4);
  P.ebuf   = (float*)alloc(2ull * 64 * 1024 * 4);
  P.sbuf   = (float*)alloc(2ull * 64 * 4);
  P.plan   = (int*)alloc(65 * 4);
  P.flagL  = (int*)alloc(64 * 4);
  P.flagH  = (int*)alloc(64 * 4);
  P.flagHid= (int*)alloc(16 * 4);

  k_init<<<dim3(256), dim3(256), 0, stream>>>(P);
  k_prep<<<dim3(256), dim3(256), 0, stream>>>(P);
  k_kv<<<dim3(256), dim3(1024), 0, stream>>>(P);

  for (int t = 0; t < 300; ++t) {
    int last = (t == 299);
    k_step<<<dim3(512), dim3(512), 0, stream>>>(P, t, last ? 0 : 1, last ? 0 : 1);
    if (t == 298) {
      k_hid<<<dim3(32), dim3(512), 0, stream>>>(P, 298);
      k_logits<<<dim3(8), dim3(512), 0, stream>>>(P, 298, 1);
    }
  }
  k_hid<<<dim3(32), dim3(512), 0, stream>>>(P, 299);
  k_attn<<<dim3(32), dim3(512), 0, stream>>>(P, 299);
  k_logits<<<dim3(8), dim3(512), 0, stream>>>(P, 299, 0);
}